// Round 3
// baseline (1092.228 us; speedup 1.0000x reference)
//
#include <hip/hip_runtime.h>
#include <math.h>

// ---------------------------------------------------------------------------
// R3: bf16-MFMA trunk, surgical glue reduction vs R2:
//  - residual H kept in fp32 REGISTERS (Rf) instead of LDS Hf (-27.6KB LDS)
//  - HbF staging via shfl_xor(1)-paired u32 writes (kills u16 bank conflicts)
//  - A_hat fragments staged once in LDS (shared by all waves, -32 VGPR)
//  LDS 62.5KB -> 43KB => 3 blocks/CU (launch_bounds(256,3)).
// Kernel B (batched split-bf16 head) unchanged.
// ---------------------------------------------------------------------------

typedef __bf16 bf16x8 __attribute__((ext_vector_type(8)));
typedef float  f32x4  __attribute__((ext_vector_type(4)));
typedef unsigned int u32x4 __attribute__((ext_vector_type(4)));

#define DEVINL __device__ __forceinline__

DEVINL unsigned bfr(float x) {             // float -> bf16 bits (RNE)
    unsigned u = __float_as_uint(x);
    return (u + 0x7fffu + ((u >> 16) & 1u)) >> 16;
}
DEVINL unsigned pk2(float a, float b) { return bfr(a) | (bfr(b) << 16); }

DEVINL f32x4 MFMA(u32x4 a, u32x4 b, f32x4 c) {
    return __builtin_amdgcn_mfma_f32_16x16x32_bf16(
        __builtin_bit_cast(bf16x8, a), __builtin_bit_cast(bf16x8, b), c, 0, 0, 0);
}

// conv acc (D-layout) + bias -> TbF (B-frag order for the mix), paired b32 writes.
DEVINL void conv_epi(f32x4 (&acc)[4][2], u32x4* TbF, int w, int g, int c15,
                     float bb0, float bb1)
{
    unsigned* p = (unsigned*)TbF;
    #pragma unroll
    for (int mt = 0; mt < 4; ++mt)
        #pragma unroll
        for (int nt = 0; nt < 2; ++nt) {
            float bb = nt ? bb1 : bb0;
            int lanep = ((mt * 2 + (g >> 1)) & 3) * 16 + c15;
            int unit  = (mt >> 1) * 8 + w * 2 + nt;
            int di = (unit * 64 + lanep) * 4 + (g & 1) * 2;
            p[di]     = pk2(acc[mt][nt][0] + bb, acc[mt][nt][1] + bb);
            p[di + 1] = pk2(acc[mt][nt][2] + bb, acc[mt][nt][3] + bb);
        }
}

// mix MFMAs: A-frags from AfL (LDS, shared), B-frags from TbF (wave-local).
DEVINL void do_mix(f32x4 (&acc)[4][2], const u32x4* TbF, const u32x4* AfL,
                   int w, int l)
{
    u32x4 bf[2][2];
    #pragma unroll
    for (int ks = 0; ks < 2; ++ks)
        #pragma unroll
        for (int nt = 0; nt < 2; ++nt)
            bf[ks][nt] = TbF[(ks * 8 + w * 2 + nt) * 64 + l];
    #pragma unroll
    for (int mt = 0; mt < 4; ++mt) {
        u32x4 a0 = AfL[(mt * 2 + 0) * 64 + l];
        u32x4 a1 = AfL[(mt * 2 + 1) * 64 + l];
        #pragma unroll
        for (int nt = 0; nt < 2; ++nt) {
            f32x4 a = {0.f, 0.f, 0.f, 0.f};
            a = MFMA(a0, bf[0][nt], a);
            a = MFMA(a1, bf[1][nt], a);
            acc[mt][nt] = a;
        }
    }
}

// mix acc -> LN(fp32 stats) -> relu -> (+resid in regs) -> Rf (fp32) + HbF (bf16)
DEVINL void mix_epi(f32x4 (&acc)[4][2], float (&Rf)[4][2][4], u32x4* HbF,
                    float (*Sred)[8], int w, int g, int c15,
                    float gc0, float gc1, float bc0, float bc1, bool resid)
{
    #pragma unroll
    for (int mt = 0; mt < 4; ++mt)
        #pragma unroll
        for (int r = 0; r < 4; ++r) {
            float v0 = acc[mt][0][r], v1 = acc[mt][1][r];
            float s = v0 + v1, q = v0 * v0 + v1 * v1;
            #pragma unroll
            for (int m = 1; m <= 8; m <<= 1) { s += __shfl_xor(s, m); q += __shfl_xor(q, m); }
            if (c15 == 0) { int row = mt * 16 + g * 4 + r; Sred[row][w] = s; Sred[row][4 + w] = q; }
        }
    __syncthreads();
    unsigned* hq = (unsigned*)HbF;
    #pragma unroll
    for (int mt = 0; mt < 4; ++mt)
        #pragma unroll
        for (int r = 0; r < 4; ++r) {
            int row = mt * 16 + g * 4 + r;
            f32x4 s4 = *(const f32x4*)&Sred[row][0];
            f32x4 q4 = *(const f32x4*)&Sred[row][4];
            float s = s4[0] + s4[1] + s4[2] + s4[3];
            float q = q4[0] + q4[1] + q4[2] + q4[3];
            float m   = s * (1.f / 128.f);
            float var = q * (1.f / 128.f) - m * m;
            float rs  = rsqrtf(var + 1e-5f);
            #pragma unroll
            for (int nt = 0; nt < 2; ++nt) {
                float gc = nt ? gc1 : gc0, bc = nt ? bc1 : bc0;
                float val = fmaxf((acc[mt][nt][r] - m) * rs * gc + bc, 0.f);
                if (resid) val += Rf[mt][nt][r];
                Rf[mt][nt][r] = val;
                // paired bf16 store: channels (c,c+1) live in adjacent c15 lanes
                float pv = __shfl_xor(val, 1);
                unsigned pair = (c15 & 1) ? pk2(pv, val) : pk2(val, pv);
                if ((c15 & 1) == (mt >> 1)) {   // even lanes write mt 0,1; odd mt 2,3
                    int lanep = ((nt * 2 + (c15 >> 3)) & 3) * 16 + g * 4 + r;
                    hq[((w * 4 + mt) * 64 + lanep) * 4 + ((c15 & 7) >> 1)] = pair;
                }
            }
        }
    __syncthreads();
}

DEVINL void conv12(f32x4 (&acc)[4][2], const u32x4* HbF, const u32x4 (&Wf)[2][4], int l)
{
    #pragma unroll
    for (int mt = 0; mt < 4; ++mt)
        #pragma unroll
        for (int nt = 0; nt < 2; ++nt) acc[mt][nt] = (f32x4){0.f, 0.f, 0.f, 0.f};
    #pragma unroll
    for (int ks = 0; ks < 4; ++ks) {
        u32x4 af[4];
        #pragma unroll
        for (int mt = 0; mt < 4; ++mt) af[mt] = HbF[(ks * 4 + mt) * 64 + l];
        #pragma unroll
        for (int mt = 0; mt < 4; ++mt)
            #pragma unroll
            for (int nt = 0; nt < 2; ++nt)
                acc[mt][nt] = MFMA(af[mt], Wf[nt][ks], acc[mt][nt]);
    }
}

// ---------------- kernel A ---------------------------------------------------
__global__ __launch_bounds__(256, 3) void gcn_mfma(
    const float* __restrict__ X, const float* __restrict__ A,
    const int* __restrict__ v1i, const int* __restrict__ v2i, const int* __restrict__ seat,
    const float* __restrict__ W0, const float* __restrict__ b0v,
    const float* __restrict__ g0v, const float* __restrict__ be0,
    const float* __restrict__ W1, const float* __restrict__ b1v,
    const float* __restrict__ g1v, const float* __restrict__ be1,
    const float* __restrict__ W2, const float* __restrict__ b2v,
    const float* __restrict__ g2v, const float* __restrict__ be2,
    const float* __restrict__ semb, float* __restrict__ hws, int spb)
{
    __shared__ u32x4 TbF[2 * 8 * 64];   // 16KB  mix B-frags (wave-local)
    __shared__ u32x4 HbF[4 * 4 * 64];   // 16KB  conv A-frags
    __shared__ u32x4 AfL[4 * 2 * 64];   // 8KB   A_hat A-frags (shared, read-only)
    __shared__ float Sred[64][8];       // 2KB   LN partials

    const int tid = threadIdx.x;
    const int l = tid & 63, w = tid >> 6, g = l >> 4, c15 = l & 15;

    // ---- persistent W fragments + LN params ----
    u32x4 W0f[2], W1f[2][4], W2f[2][4];
    float gcs[3][2], bcs[3][2], bbs[3][2];

    #pragma unroll
    for (int nt = 0; nt < 2; ++nt) {
        const int col = w * 32 + nt * 16 + c15;
        #pragma unroll
        for (int ks = 0; ks < 4; ++ks) {
            unsigned t1[4], t2[4];
            #pragma unroll
            for (int jj = 0; jj < 4; ++jj) {
                int k = ks * 32 + g * 8 + 2 * jj;
                t1[jj] = pk2(W1[k * 128 + col], W1[(k + 1) * 128 + col]);
                t2[jj] = pk2(W2[k * 128 + col], W2[(k + 1) * 128 + col]);
            }
            W1f[nt][ks] = (u32x4){t1[0], t1[1], t1[2], t1[3]};
            W2f[nt][ks] = (u32x4){t2[0], t2[1], t2[2], t2[3]};
        }
        {
            unsigned t[4];
            #pragma unroll
            for (int jj = 0; jj < 4; ++jj) {
                int k = g * 8 + 2 * jj;
                t[jj] = (k < 16) ? pk2(W0[k * 128 + col], W0[(k + 1) * 128 + col]) : 0u;
            }
            W0f[nt] = (u32x4){t[0], t[1], t[2], t[3]};
        }
        gcs[0][nt] = g0v[col]; bcs[0][nt] = be0[col]; bbs[0][nt] = b0v[col];
        gcs[1][nt] = g1v[col]; bcs[1][nt] = be1[col]; bbs[1][nt] = b1v[col];
        gcs[2][nt] = g2v[col]; bcs[2][nt] = be2[col]; bbs[2][nt] = b2v[col];
    }
    // A_hat fragments -> LDS (wave 0 builds; identical for all waves)
    if (w == 0) {
        #pragma unroll
        for (int mt = 0; mt < 4; ++mt) {
            int row = mt * 16 + c15;
            #pragma unroll
            for (int ks = 0; ks < 2; ++ks) {
                unsigned t[4];
                #pragma unroll
                for (int jj = 0; jj < 4; ++jj) {
                    int k = ks * 32 + g * 8 + 2 * jj;
                    float va = (row < 54 && k     < 54) ? A[row * 54 + k]     : 0.f;
                    float vb = (row < 54 && k + 1 < 54) ? A[row * 54 + k + 1] : 0.f;
                    t[jj] = pk2(va, vb);
                }
                AfL[(mt * 2 + ks) * 64 + l] = (u32x4){t[0], t[1], t[2], t[3]};
            }
        }
    }
    __syncthreads();

    float Rf[4][2][4];   // fp32 residual H, this lane's (row,col) elements

    // ---- sample loop ----
    #pragma unroll 1
    for (int it = 0; it < spb; ++it) {
        const int n = blockIdx.x + gridDim.x * it;

        // conv0: A-frags straight from global X (K=16, zero-padded to 32)
        f32x4 acc[4][2];
        #pragma unroll
        for (int mt = 0; mt < 4; ++mt)
            #pragma unroll
            for (int nt = 0; nt < 2; ++nt) acc[mt][nt] = (f32x4){0.f, 0.f, 0.f, 0.f};
        #pragma unroll
        for (int mt = 0; mt < 4; ++mt) {
            int row = mt * 16 + c15;
            u32x4 af;
            if (g < 2 && row < 54) {
                const f32x4* xp = (const f32x4*)(X + (size_t)n * 864 + row * 16 + g * 8);
                f32x4 f0 = xp[0], f1 = xp[1];
                af = (u32x4){pk2(f0[0], f0[1]), pk2(f0[2], f0[3]),
                             pk2(f1[0], f1[1]), pk2(f1[2], f1[3])};
            } else af = (u32x4){0u, 0u, 0u, 0u};
            #pragma unroll
            for (int nt = 0; nt < 2; ++nt) acc[mt][nt] = MFMA(af, W0f[nt], acc[mt][nt]);
        }
        conv_epi(acc, TbF, w, g, c15, bbs[0][0], bbs[0][1]);
        do_mix(acc, TbF, AfL, w, l);
        mix_epi(acc, Rf, HbF, Sred, w, g, c15, gcs[0][0], gcs[0][1], bcs[0][0], bcs[0][1], false);

        conv12(acc, HbF, W1f, l);
        conv_epi(acc, TbF, w, g, c15, bbs[1][0], bbs[1][1]);
        do_mix(acc, TbF, AfL, w, l);
        mix_epi(acc, Rf, HbF, Sred, w, g, c15, gcs[1][0], gcs[1][1], bcs[1][0], bcs[1][1], true);

        conv12(acc, HbF, W2f, l);
        conv_epi(acc, TbF, w, g, c15, bbs[2][0], bbs[2][1]);
        do_mix(acc, TbF, AfL, w, l);
        mix_epi(acc, Rf, HbF, Sred, w, g, c15, gcs[2][0], gcs[2][1], bcs[2][0], bcs[2][1], true);

        // ---- head features straight from Rf (fp32) -> hws [N][416] ----
        int v1 = v1i[n], v2 = v2i[n], st = seat[n];
        st = st < 0 ? 0 : (st > 3 ? 3 : st);
        float* hr = hws + (size_t)n * 416;

        // v1/v2 gather: exec-masked stores (compile-time reg indices)
        #pragma unroll
        for (int mt = 0; mt < 4; ++mt)
            #pragma unroll
            for (int r = 0; r < 4; ++r) {
                int rowv = mt * 16 + g * 4 + r;
                bool h1 = (rowv == v1), h2 = (rowv == v2);
                #pragma unroll
                for (int nt = 0; nt < 2; ++nt) {
                    int c = w * 32 + nt * 16 + c15;
                    if (h1) hr[c]       = Rf[mt][nt][r];
                    if (h2) hr[128 + c] = Rf[mt][nt][r];
                }
            }
        // mean over verts: in-lane masked sum + cross-g shuffles
        #pragma unroll
        for (int nt = 0; nt < 2; ++nt) {
            float s = 0.f;
            #pragma unroll
            for (int mt = 0; mt < 3; ++mt)
                #pragma unroll
                for (int r = 0; r < 4; ++r) s += Rf[mt][nt][r];
            #pragma unroll
            for (int r = 0; r < 4; ++r)
                if (g * 4 + r < 6) s += Rf[3][nt][r];   // rows 48..53
            s += __shfl_xor(s, 16);
            s += __shfl_xor(s, 32);
            if (g == 0) hr[256 + w * 32 + nt * 16 + c15] = s * (1.f / 54.f);
        }
        if (tid < 8)       hr[384 + tid] = semb[st * 8 + tid];
        else if (tid < 32) hr[384 + tid] = 0.f;   // pad cols 392..415
    }
}

// ---------------- kernel B: batched head (unchanged) -------------------------
__global__ __launch_bounds__(256, 2) void head_mfma(
    const float* __restrict__ hws,
    const float* __restrict__ mW1, const float* __restrict__ mb1,
    const float* __restrict__ mW2, const float* __restrict__ mb2,
    const float* __restrict__ mW3, const float* __restrict__ mb3,
    const float* __restrict__ rW1, const float* __restrict__ rb1,
    const float* __restrict__ rW2, const float* __restrict__ rb2,
    float* __restrict__ out, int N)
{
    __shared__ u32x4 pool[2048];          // 32KB
    u32x4* SW1h = pool;
    u32x4* SW1l = pool + 512;
    u32x4* SR1h = pool + 1024;
    u32x4* Zh   = pool;
    u32x4* SW2h = pool + 1024;

    const int tid = threadIdx.x, l = tid & 63, w = tid >> 6, g = l >> 4, c15 = l & 15;
    const int row = blockIdx.x * 64 + w * 16 + c15;

    f32x4 z1[8], rr[4];
    #pragma unroll
    for (int i = 0; i < 8; ++i) z1[i] = (f32x4){0.f, 0.f, 0.f, 0.f};
    #pragma unroll
    for (int i = 0; i < 4; ++i) rr[i] = (f32x4){0.f, 0.f, 0.f, 0.f};

    for (int ks = 0; ks < 13; ++ks) {
        {
            int col = tid & 127, kbase = (tid >> 7) * 16;
            unsigned short* ph = (unsigned short*)SW1h;
            unsigned short* pl = (unsigned short*)SW1l;
            #pragma unroll
            for (int kk = 0; kk < 16; ++kk) {
                int kloc = kbase + kk, k = ks * 32 + kloc;
                float wv = (k < 392) ? mW1[k * 128 + col] : 0.f;
                unsigned hi = bfr(wv);
                float lof = wv - __uint_as_float(hi << 16);
                int idx = ((col >> 4) * 64 + ((kloc >> 3) & 3) * 16 + (col & 15)) * 8 + (kloc & 7);
                ph[idx] = (unsigned short)hi;
                pl[idx] = (unsigned short)bfr(lof);
            }
            int col2 = tid & 63, kb2 = (tid >> 6) * 8;
            unsigned short* pr = (unsigned short*)SR1h;
            #pragma unroll
            for (int kk = 0; kk < 8; ++kk) {
                int kloc = kb2 + kk, k = ks * 32 + kloc;
                float wv = (k < 392) ? rW1[k * 64 + col2] : 0.f;
                pr[((col2 >> 4) * 64 + ((kloc >> 3) & 3) * 16 + (col2 & 15)) * 8 + (kloc & 7)]
                    = (unsigned short)bfr(wv);
            }
        }
        __syncthreads();
        const float* hp = hws + (size_t)row * 416 + ks * 32 + g * 8;
        f32x4 f0 = *(const f32x4*)hp, f1 = *(const f32x4*)(hp + 4);
        float vv[8] = {f0[0], f0[1], f0[2], f0[3], f1[0], f1[1], f1[2], f1[3]};
        unsigned th[4], tl[4];
        #pragma unroll
        for (int jj = 0; jj < 4; ++jj) {
            unsigned ha = bfr(vv[2 * jj]), hb = bfr(vv[2 * jj + 1]);
            th[jj] = ha | (hb << 16);
            tl[jj] = pk2(vv[2 * jj] - __uint_as_float(ha << 16),
                         vv[2 * jj + 1] - __uint_as_float(hb << 16));
        }
        u32x4 ah = (u32x4){th[0], th[1], th[2], th[3]};
        u32x4 al = (u32x4){tl[0], tl[1], tl[2], tl[3]};
        #pragma unroll
        for (int nt = 0; nt < 8; ++nt) {
            u32x4 bh = SW1h[nt * 64 + l], bl = SW1l[nt * 64 + l];
            f32x4 a = z1[nt];
            a = MFMA(ah, bh, a); a = MFMA(ah, bl, a); a = MFMA(al, bh, a);
            z1[nt] = a;
        }
        #pragma unroll
        for (int nt = 0; nt < 4; ++nt) rr[nt] = MFMA(ah, SR1h[nt * 64 + l], rr[nt]);
        __syncthreads();
    }

    float rp[4] = {0.f, 0.f, 0.f, 0.f};
    #pragma unroll
    for (int nt = 0; nt < 4; ++nt) {
        int c = nt * 16 + c15;
        float rb = rb1[c], rw = rW2[c];
        #pragma unroll
        for (int r = 0; r < 4; ++r) rp[r] += fmaxf(rr[nt][r] + rb, 0.f) * rw;
    }
    #pragma unroll
    for (int r = 0; r < 4; ++r) {
        float p = rp[r];
        #pragma unroll
        for (int m = 1; m <= 8; m <<= 1) p += __shfl_xor(p, m);
        if (c15 == 0) {
            int orow = blockIdx.x * 64 + w * 16 + g * 4 + r;
            out[N + orow] = 1.f / (1.f + expf(-(p + rb2[0])));
        }
    }

    {
        unsigned short* zp = (unsigned short*)Zh;
        #pragma unroll
        for (int nt = 0; nt < 8; ++nt) {
            int c = nt * 16 + c15;
            float bb = mb1[c];
            #pragma unroll
            for (int r = 0; r < 4; ++r) {
                float v = fmaxf(z1[nt][r] + bb, 0.f);
                int lanep = ((nt * 2 + (c15 >> 3)) & 3) * 16 + g * 4 + r;
                zp[((w * 4 + (nt >> 1)) * 64 + lanep) * 8 + (c15 & 7)] = (unsigned short)bfr(v);
            }
        }
        unsigned short* p2 = (unsigned short*)SW2h;
        int col2 = tid & 63, kb = (tid >> 6) * 32;
        #pragma unroll
        for (int kk = 0; kk < 32; ++kk) {
            int k2 = kb + kk;
            p2[(((k2 >> 5) * 4 + (col2 >> 4)) * 64 + ((k2 >> 3) & 3) * 16 + (col2 & 15)) * 8 + (k2 & 7)]
                = (unsigned short)bfr(mW2[k2 * 64 + col2]);
        }
    }
    __syncthreads();

    f32x4 z2a[4];
    #pragma unroll
    for (int i = 0; i < 4; ++i) z2a[i] = (f32x4){0.f, 0.f, 0.f, 0.f};
    #pragma unroll
    for (int ks2 = 0; ks2 < 4; ++ks2) {
        u32x4 za = Zh[(w * 4 + ks2) * 64 + l];
        #pragma unroll
        for (int nt2 = 0; nt2 < 4; ++nt2)
            z2a[nt2] = MFMA(za, SW2h[(ks2 * 4 + nt2) * 64 + l], z2a[nt2]);
    }
    float wp[4] = {0.f, 0.f, 0.f, 0.f};
    #pragma unroll
    for (int nt2 = 0; nt2 < 4; ++nt2) {
        int c = nt2 * 16 + c15;
        float bb = mb2[c], w3 = mW3[c];
        #pragma unroll
        for (int r = 0; r < 4; ++r) wp[r] += fmaxf(z2a[nt2][r] + bb, 0.f) * w3;
    }
    #pragma unroll
    for (int r = 0; r < 4; ++r) {
        float p = wp[r];
        #pragma unroll
        for (int m = 1; m <= 8; m <<= 1) p += __shfl_xor(p, m);
        if (c15 == 0) {
            int orow = blockIdx.x * 64 + w * 16 + g * 4 + r;
            out[orow] = p + mb3[0];
        }
    }
}

extern "C" void kernel_launch(void* const* d_in, const int* in_sizes, int n_in,
                              void* d_out, int out_size, void* d_ws, size_t ws_size,
                              hipStream_t stream) {
    const float* X        = (const float*)d_in[0];
    const float* A        = (const float*)d_in[1];
    const int*   v1_idx   = (const int*)d_in[2];
    const int*   v2_idx   = (const int*)d_in[3];
    const int*   seat     = (const int*)d_in[4];
    const float* W0       = (const float*)d_in[5];
    const float* b0       = (const float*)d_in[6];
    const float* g0       = (const float*)d_in[7];
    const float* be0      = (const float*)d_in[8];
    const float* W1       = (const float*)d_in[9];
    const float* b1       = (const float*)d_in[10];
    const float* g1       = (const float*)d_in[11];
    const float* be1      = (const float*)d_in[12];
    const float* W2       = (const float*)d_in[13];
    const float* b2       = (const float*)d_in[14];
    const float* g2       = (const float*)d_in[15];
    const float* be2      = (const float*)d_in[16];
    const float* seat_emb = (const float*)d_in[17];
    const float* mW1      = (const float*)d_in[18];
    const float* mb1      = (const float*)d_in[19];
    const float* mW2      = (const float*)d_in[20];
    const float* mb2      = (const float*)d_in[21];
    const float* mW3      = (const float*)d_in[22];
    const float* mb3      = (const float*)d_in[23];
    const float* rW1      = (const float*)d_in[24];
    const float* rb1      = (const float*)d_in[25];
    const float* rW2      = (const float*)d_in[26];
    const float* rb2      = (const float*)d_in[27];

    const int N = in_sizes[2];           // 16384
    float* out = (float*)d_out;
    float* hws = (float*)d_ws;           // N*416*4 = 27.3MB

    const int spb = 8;
    const int gridA = N / spb;           // 2048
    gcn_mfma<<<gridA, 256, 0, stream>>>(
        X, A, v1_idx, v2_idx, seat,
        W0, b0, g0, be0, W1, b1, g1, be1, W2, b2, g2, be2,
        seat_emb, hws, spb);

    const int gridB = N / 64;            // 256
    head_mfma<<<gridB, 256, 0, stream>>>(
        hws, mW1, mb1, mW2, mb2, mW3, mb3, rW1, rb1, rW2, rb2, out, N);
}

// Round 4
// 574.156 us; speedup vs baseline: 1.9023x; 1.9023x over previous
//
#include <hip/hip_runtime.h>
#include <math.h>

// ---------------------------------------------------------------------------
// R4: "transposed-world" bf16-MFMA trunk.
//   conv:  T2 = W^T * H      (A-op = W^T frags in regs, B-op = H row-major LDS)
//   mix:   out2 = T2 * Amix^T (A-op = T2 row-major LDS, B-op = Amix row-major LDS)
//   => mix output has CHANNELS in registers, ONE VERTEX per lane:
//      LN = 31 in-thread adds + 2 shuffles (no Sred LDS round-trip, no barrier).
//   LDS tiles are plain row-major bf16 with padded strides (36 / 68 u32)
//   => b128-aligned reads, <=2-way bank conflicts on the hot paths.
//   Residual H in fp32 registers (Rf[8][4]); launch_bounds(256,2) (no R3 spill).
// Kernel B (batched split-bf16 head) unchanged from R2/R3.
// ---------------------------------------------------------------------------

typedef __bf16 bf16x8 __attribute__((ext_vector_type(8)));
typedef float  f32x4  __attribute__((ext_vector_type(4)));
typedef unsigned int u32x4 __attribute__((ext_vector_type(4)));
typedef unsigned int u32x2 __attribute__((ext_vector_type(2)));

#define DEVINL __device__ __forceinline__

DEVINL unsigned bfr(float x) {             // float -> bf16 bits (RNE)
    unsigned u = __float_as_uint(x);
    return (u + 0x7fffu + ((u >> 16) & 1u)) >> 16;
}
DEVINL unsigned pk2(float a, float b) { return bfr(a) | (bfr(b) << 16); }

DEVINL f32x4 MFMA(u32x4 a, u32x4 b, f32x4 c) {
    return __builtin_amdgcn_mfma_f32_16x16x32_bf16(
        __builtin_bit_cast(bf16x8, a), __builtin_bit_cast(bf16x8, b), c, 0, 0, 0);
}

#define TS 36   // Tlds / Amlds row stride in u32 (pairs of bf16); 36%4==0, bank-friendly
#define HS 68   // Hlds row stride in u32

// conv layers 1,2: acc[m2][ut] = (W^T)_tile x H-as-B
DEVINL void conv12(f32x4 (&acc)[2][4], const unsigned* Hlds,
                   const u32x4 (&Wf)[2][4], int g, int c15)
{
    #pragma unroll
    for (int m2 = 0; m2 < 2; ++m2)
        #pragma unroll
        for (int ut = 0; ut < 4; ++ut) acc[m2][ut] = (f32x4){0.f, 0.f, 0.f, 0.f};
    #pragma unroll
    for (int ks = 0; ks < 4; ++ks) {
        u32x4 hb[4];
        #pragma unroll
        for (int ut = 0; ut < 4; ++ut)
            hb[ut] = *(const u32x4*)&Hlds[(ut * 16 + c15) * HS + ks * 16 + g * 4];
        #pragma unroll
        for (int m2 = 0; m2 < 2; ++m2)
            #pragma unroll
            for (int ut = 0; ut < 4; ++ut)
                acc[m2][ut] = MFMA(Wf[m2][ks], hb[ut], acc[m2][ut]);
    }
}

// conv epilogue: acc + bias -> Tlds (row-major bf16 pairs along u)
DEVINL void conv_epi(const f32x4 (&acc)[2][4], unsigned* Tlds, const float* bias,
                     int w, int g, int c15)
{
    #pragma unroll
    for (int m2 = 0; m2 < 2; ++m2) {
        const int chb = (2 * w + m2) * 16;
        f32x4 bb = *(const f32x4*)&bias[chb + g * 4];
        #pragma unroll
        for (int ut = 0; ut < 4; ++ut)
            #pragma unroll
            for (int r = 0; r < 4; ++r) {
                float val = acc[m2][ut][r] + bb[r];
                float pv  = __shfl_xor(val, 1);
                if ((c15 & 1) == m2) {
                    unsigned pair = (c15 & 1) ? pk2(pv, val) : pk2(val, pv);
                    Tlds[(chb + g * 4 + r) * TS + ut * 8 + (c15 >> 1)] = pair;
                }
            }
    }
}

// mix: macc[mt'] = T2_tile x Amix^T   (vertex = lane c15, wave owns v-tile w)
DEVINL void do_mix(f32x4 (&macc)[8], const unsigned* Tlds, const unsigned* Amlds,
                   int w, int g, int c15)
{
    const int vrow = (w * 16 + c15) * TS + g * 4;
    u32x4 bf0 = *(const u32x4*)&Amlds[vrow];
    u32x4 bf1 = *(const u32x4*)&Amlds[vrow + 16];
    #pragma unroll
    for (int mt = 0; mt < 8; ++mt) {
        const int crow = (mt * 16 + c15) * TS + g * 4;
        u32x4 a0 = *(const u32x4*)&Tlds[crow];
        u32x4 a1 = *(const u32x4*)&Tlds[crow + 16];
        f32x4 a = {0.f, 0.f, 0.f, 0.f};
        a = MFMA(a0, bf0, a);
        a = MFMA(a1, bf1, a);
        macc[mt] = a;
    }
}

// mix epilogue: LN (in-wave) + relu + residual -> Rf; optionally write H to LDS
DEVINL void mix_epi(const f32x4 (&macc)[8], float (&Rf)[8][4], unsigned* Hlds,
                    const float* gam, const float* bet, bool resid, bool writeH,
                    int w, int g, int c15)
{
    float s = 0.f, q = 0.f;
    #pragma unroll
    for (int mt = 0; mt < 8; ++mt)
        #pragma unroll
        for (int r = 0; r < 4; ++r) { float x = macc[mt][r]; s += x; q = fmaf(x, x, q); }
    s += __shfl_xor(s, 16); s += __shfl_xor(s, 32);
    q += __shfl_xor(q, 16); q += __shfl_xor(q, 32);
    const float m   = s * (1.f / 128.f);
    const float var = q * (1.f / 128.f) - m * m;
    const float rs  = rsqrtf(var + 1e-5f);
    const int v = w * 16 + c15;
    #pragma unroll
    for (int mt = 0; mt < 8; ++mt) {
        f32x4 gc = *(const f32x4*)&gam[mt * 16 + g * 4];
        f32x4 bc = *(const f32x4*)&bet[mt * 16 + g * 4];
        #pragma unroll
        for (int r = 0; r < 4; ++r) {
            float val = fmaxf((macc[mt][r] - m) * rs * gc[r] + bc[r], 0.f);
            if (resid) val += Rf[mt][r];
            Rf[mt][r] = val;
        }
        if (writeH) {
            u32x2 pr;
            pr[0] = pk2(Rf[mt][0], Rf[mt][1]);
            pr[1] = pk2(Rf[mt][2], Rf[mt][3]);
            *(u32x2*)&Hlds[v * HS + mt * 8 + g * 2] = pr;
        }
    }
}

// ---------------- kernel A ---------------------------------------------------
__global__ __launch_bounds__(256, 2) void gcn_mfma(
    const float* __restrict__ X, const float* __restrict__ A,
    const int* __restrict__ v1i, const int* __restrict__ v2i, const int* __restrict__ seat,
    const float* __restrict__ W0, const float* __restrict__ b0v,
    const float* __restrict__ g0v, const float* __restrict__ be0,
    const float* __restrict__ W1, const float* __restrict__ b1v,
    const float* __restrict__ g1v, const float* __restrict__ be1,
    const float* __restrict__ W2, const float* __restrict__ b2v,
    const float* __restrict__ g2v, const float* __restrict__ be2,
    const float* __restrict__ semb, float* __restrict__ hws, int spb)
{
    __shared__ unsigned Tlds[128 * TS];   // 18.4KB  T2 row-major [ch][u-pairs]
    __shared__ unsigned Hlds[64 * HS];    // 17.4KB  H  row-major [v][ch-pairs]
    __shared__ unsigned Amlds[64 * TS];   // 9.2KB   Amix row-major [v][u-pairs]
    __shared__ float    PrmL[9][128];     // 4.6KB   bias0..2 | gam0..2 | bet0..2
    __shared__ float    Sm[4][128];       // 2KB     per-wave mean partials

    const int tid = threadIdx.x;
    const int l = tid & 63, w = tid >> 6, g = l >> 4, c15 = l & 15;

    // ---- param tables ----
    if (tid < 128) {
        const int c = tid;
        PrmL[0][c] = b0v[c]; PrmL[1][c] = b1v[c]; PrmL[2][c] = b2v[c];
        PrmL[3][c] = g0v[c]; PrmL[4][c] = g1v[c]; PrmL[5][c] = g2v[c];
        PrmL[6][c] = be0[c]; PrmL[7][c] = be1[c]; PrmL[8][c] = be2[c];
    }
    // ---- Amix row-major bf16 (v<54, u<54 valid, else 0) ----
    for (int p = tid; p < 64 * TS; p += 256) {
        const int v = p / TS, uc = p % TS;
        unsigned val = 0u;
        if (v < 54 && uc < 27) {
            const int u = uc * 2;
            const float a0 = A[v * 54 + u];
            const float a1 = (u + 1 < 54) ? A[v * 54 + u + 1] : 0.f;
            val = pk2(a0, a1);
        }
        Amlds[p] = val;
    }

    // ---- persistent W^T A-fragments (per wave: ch-tiles 2w, 2w+1) ----
    u32x4 W0f[2], W1f[2][4], W2f[2][4];
    #pragma unroll
    for (int m2 = 0; m2 < 2; ++m2) {
        const int ch = (2 * w + m2) * 16 + c15;
        #pragma unroll
        for (int ks = 0; ks < 4; ++ks) {
            unsigned t1[4], t2[4];
            #pragma unroll
            for (int jj = 0; jj < 4; ++jj) {
                const int k = ks * 32 + g * 8 + 2 * jj;
                t1[jj] = pk2(W1[k * 128 + ch], W1[(k + 1) * 128 + ch]);
                t2[jj] = pk2(W2[k * 128 + ch], W2[(k + 1) * 128 + ch]);
            }
            W1f[m2][ks] = (u32x4){t1[0], t1[1], t1[2], t1[3]};
            W2f[m2][ks] = (u32x4){t2[0], t2[1], t2[2], t2[3]};
        }
        unsigned t0[4];
        #pragma unroll
        for (int jj = 0; jj < 4; ++jj) {
            const int k = g * 8 + 2 * jj;
            t0[jj] = (g < 2) ? pk2(W0[k * 128 + ch], W0[(k + 1) * 128 + ch]) : 0u;
        }
        W0f[m2] = (u32x4){t0[0], t0[1], t0[2], t0[3]};
    }
    __syncthreads();

    float Rf[8][4];      // fp32 residual H: this lane's vertex, channels mt*16+g*4+r
    f32x4 acc[2][4];     // conv accumulators
    f32x4 macc[8];       // mix accumulators

    #pragma unroll 1
    for (int it = 0; it < spb; ++it) {
        const int n = blockIdx.x + gridDim.x * it;

        // ---- conv0: T2 = W0^T * X2 (K=16 zero-padded to 32) ----
        #pragma unroll
        for (int m2 = 0; m2 < 2; ++m2)
            #pragma unroll
            for (int ut = 0; ut < 4; ++ut) acc[m2][ut] = (f32x4){0.f, 0.f, 0.f, 0.f};
        #pragma unroll
        for (int ut = 0; ut < 4; ++ut) {
            const int u = ut * 16 + c15;
            u32x4 xb = (u32x4){0u, 0u, 0u, 0u};
            if (g < 2 && u < 54) {
                const f32x4* xp = (const f32x4*)(X + (size_t)n * 864 + u * 16 + g * 8);
                f32x4 f0 = xp[0], f1 = xp[1];
                xb = (u32x4){pk2(f0[0], f0[1]), pk2(f0[2], f0[3]),
                             pk2(f1[0], f1[1]), pk2(f1[2], f1[3])};
            }
            #pragma unroll
            for (int m2 = 0; m2 < 2; ++m2)
                acc[m2][ut] = MFMA(W0f[m2], xb, acc[m2][ut]);
        }
        conv_epi(acc, Tlds, &PrmL[0][0], w, g, c15);
        __syncthreads();
        do_mix(macc, Tlds, Amlds, w, g, c15);
        mix_epi(macc, Rf, Hlds, &PrmL[3][0], &PrmL[6][0], false, true, w, g, c15);
        __syncthreads();

        // ---- layer 1 ----
        conv12(acc, Hlds, W1f, g, c15);
        conv_epi(acc, Tlds, &PrmL[1][0], w, g, c15);
        __syncthreads();
        do_mix(macc, Tlds, Amlds, w, g, c15);
        mix_epi(macc, Rf, Hlds, &PrmL[4][0], &PrmL[7][0], true, true, w, g, c15);
        __syncthreads();

        // ---- layer 2 ----
        conv12(acc, Hlds, W2f, g, c15);
        conv_epi(acc, Tlds, &PrmL[2][0], w, g, c15);
        __syncthreads();
        do_mix(macc, Tlds, Amlds, w, g, c15);
        mix_epi(macc, Rf, Hlds, &PrmL[5][0], &PrmL[8][0], true, false, w, g, c15);

        // ---- head features -> hws [N][416] ----
        const int v1 = v1i[n], v2 = v2i[n];
        int st = seat[n];
        st = st < 0 ? 0 : (st > 3 ? 3 : st);
        float* hr = hws + (size_t)n * 416;
        const int v = w * 16 + c15;

        // v1/v2 gather: the 4 g-lanes of the matching vertex write its 128 chs
        if (v == v1 || v == v2) {
            #pragma unroll
            for (int mt = 0; mt < 8; ++mt) {
                f32x4 t;
                #pragma unroll
                for (int r = 0; r < 4; ++r) t[r] = Rf[mt][r];
                if (v == v1) *(f32x4*)&hr[mt * 16 + g * 4] = t;
                if (v == v2) *(f32x4*)&hr[128 + mt * 16 + g * 4] = t;
            }
        }

        // mean over verts: multi-value butterfly over c15 (30 shfl), then Sm
        {
            const bool vok = (v < 54);
            float t16[16];
            #pragma unroll
            for (int jj = 0; jj < 16; ++jj) {
                float a = vok ? Rf[(2*jj) >> 2][(2*jj) & 3] : 0.f;
                float b = vok ? Rf[(2*jj+1) >> 2][(2*jj+1) & 3] : 0.f;
                float mine = (c15 & 1) ? b : a;
                float oth  = (c15 & 1) ? a : b;
                t16[jj] = mine + __shfl_xor(oth, 1);
            }
            float t8[8];
            #pragma unroll
            for (int jj = 0; jj < 8; ++jj) {
                float a = t16[2*jj], b = t16[2*jj+1];
                float mine = (c15 & 2) ? b : a;
                float oth  = (c15 & 2) ? a : b;
                t8[jj] = mine + __shfl_xor(oth, 2);
            }
            float t4[4];
            #pragma unroll
            for (int jj = 0; jj < 4; ++jj) {
                float a = t8[2*jj], b = t8[2*jj+1];
                float mine = (c15 & 4) ? b : a;
                float oth  = (c15 & 4) ? a : b;
                t4[jj] = mine + __shfl_xor(oth, 4);
            }
            float t2a[2];
            #pragma unroll
            for (int jj = 0; jj < 2; ++jj) {
                float a = t4[2*jj], b = t4[2*jj+1];
                float mine = (c15 & 8) ? b : a;
                float oth  = (c15 & 8) ? a : b;
                t2a[jj] = mine + __shfl_xor(oth, 8);
            }
            // lane c15 now holds full-16-lane sums for j=c15 and j=16+c15,
            // where j = (mt&3)*4 + r  ->  ch = ((c15>>2)+4h)*16 + g*4 + (c15&3)
            const int ch1 = (c15 >> 2) * 16 + g * 4 + (c15 & 3);
            Sm[w][ch1]      = t2a[0];
            Sm[w][ch1 + 64] = t2a[1];
        }
        __syncthreads();
        if (tid < 128) {
            const float mn = (Sm[0][tid] + Sm[1][tid] + Sm[2][tid] + Sm[3][tid]) * (1.f / 54.f);
            hr[256 + tid] = mn;
        }
        if (tid < 8)       hr[384 + tid] = semb[st * 8 + tid];
        else if (tid < 32) hr[384 + tid] = 0.f;
    }
}

// ---------------- kernel B: batched head (unchanged) -------------------------
__global__ __launch_bounds__(256, 2) void head_mfma(
    const float* __restrict__ hws,
    const float* __restrict__ mW1, const float* __restrict__ mb1,
    const float* __restrict__ mW2, const float* __restrict__ mb2,
    const float* __restrict__ mW3, const float* __restrict__ mb3,
    const float* __restrict__ rW1, const float* __restrict__ rb1,
    const float* __restrict__ rW2, const float* __restrict__ rb2,
    float* __restrict__ out, int N)
{
    __shared__ u32x4 pool[2048];          // 32KB
    u32x4* SW1h = pool;
    u32x4* SW1l = pool + 512;
    u32x4* SR1h = pool + 1024;
    u32x4* Zh   = pool;
    u32x4* SW2h = pool + 1024;

    const int tid = threadIdx.x, l = tid & 63, w = tid >> 6, g = l >> 4, c15 = l & 15;
    const int row = blockIdx.x * 64 + w * 16 + c15;

    f32x4 z1[8], rr[4];
    #pragma unroll
    for (int i = 0; i < 8; ++i) z1[i] = (f32x4){0.f, 0.f, 0.f, 0.f};
    #pragma unroll
    for (int i = 0; i < 4; ++i) rr[i] = (f32x4){0.f, 0.f, 0.f, 0.f};

    for (int ks = 0; ks < 13; ++ks) {
        {
            int col = tid & 127, kbase = (tid >> 7) * 16;
            unsigned short* ph = (unsigned short*)SW1h;
            unsigned short* pl = (unsigned short*)SW1l;
            #pragma unroll
            for (int kk = 0; kk < 16; ++kk) {
                int kloc = kbase + kk, k = ks * 32 + kloc;
                float wv = (k < 392) ? mW1[k * 128 + col] : 0.f;
                unsigned hi = bfr(wv);
                float lof = wv - __uint_as_float(hi << 16);
                int idx = ((col >> 4) * 64 + ((kloc >> 3) & 3) * 16 + (col & 15)) * 8 + (kloc & 7);
                ph[idx] = (unsigned short)hi;
                pl[idx] = (unsigned short)bfr(lof);
            }
            int col2 = tid & 63, kb2 = (tid >> 6) * 8;
            unsigned short* pr = (unsigned short*)SR1h;
            #pragma unroll
            for (int kk = 0; kk < 8; ++kk) {
                int kloc = kb2 + kk, k = ks * 32 + kloc;
                float wv = (k < 392) ? rW1[k * 64 + col2] : 0.f;
                pr[((col2 >> 4) * 64 + ((kloc >> 3) & 3) * 16 + (col2 & 15)) * 8 + (kloc & 7)]
                    = (unsigned short)bfr(wv);
            }
        }
        __syncthreads();
        const float* hp = hws + (size_t)row * 416 + ks * 32 + g * 8;
        f32x4 f0 = *(const f32x4*)hp, f1 = *(const f32x4*)(hp + 4);
        float vv[8] = {f0[0], f0[1], f0[2], f0[3], f1[0], f1[1], f1[2], f1[3]};
        unsigned th[4], tl[4];
        #pragma unroll
        for (int jj = 0; jj < 4; ++jj) {
            unsigned ha = bfr(vv[2 * jj]), hb = bfr(vv[2 * jj + 1]);
            th[jj] = ha | (hb << 16);
            tl[jj] = pk2(vv[2 * jj] - __uint_as_float(ha << 16),
                         vv[2 * jj + 1] - __uint_as_float(hb << 16));
        }
        u32x4 ah = (u32x4){th[0], th[1], th[2], th[3]};
        u32x4 al = (u32x4){tl[0], tl[1], tl[2], tl[3]};
        #pragma unroll
        for (int nt = 0; nt < 8; ++nt) {
            u32x4 bh = SW1h[nt * 64 + l], bl = SW1l[nt * 64 + l];
            f32x4 a = z1[nt];
            a = MFMA(ah, bh, a); a = MFMA(ah, bl, a); a = MFMA(al, bh, a);
            z1[nt] = a;
        }
        #pragma unroll
        for (int nt = 0; nt < 4; ++nt) rr[nt] = MFMA(ah, SR1h[nt * 64 + l], rr[nt]);
        __syncthreads();
    }

    float rp[4] = {0.f, 0.f, 0.f, 0.f};
    #pragma unroll
    for (int nt = 0; nt < 4; ++nt) {
        int c = nt * 16 + c15;
        float rb = rb1[c], rw = rW2[c];
        #pragma unroll
        for (int r = 0; r < 4; ++r) rp[r] += fmaxf(rr[nt][r] + rb, 0.f) * rw;
    }
    #pragma unroll
    for (int r = 0; r < 4; ++r) {
        float p = rp[r];
        #pragma unroll
        for (int m = 1; m <= 8; m <<= 1) p += __shfl_xor(p, m);
        if (c15 == 0) {
            int orow = blockIdx.x * 64 + w * 16 + g * 4 + r;
            out[N + orow] = 1.f / (1.f + expf(-(p + rb2[0])));
        }
    }

    {
        unsigned short* zp = (unsigned short*)Zh;
        #pragma unroll
        for (int nt = 0; nt < 8; ++nt) {
            int c = nt * 16 + c15;
            float bb = mb1[c];
            #pragma unroll
            for (int r = 0; r < 4; ++r) {
                float v = fmaxf(z1[nt][r] + bb, 0.f);
                int lanep = ((nt * 2 + (c15 >> 3)) & 3) * 16 + g * 4 + r;
                zp[((w * 4 + (nt >> 1)) * 64 + lanep) * 8 + (c15 & 7)] = (unsigned short)bfr(v);
            }
        }
        unsigned short* p2 = (unsigned short*)SW2h;
        int col2 = tid & 63, kb = (tid >> 6) * 32;
        #pragma unroll
        for (int kk = 0; kk < 32; ++kk) {
            int k2 = kb + kk;
            p2[(((k2 >> 5) * 4 + (col2 >> 4)) * 64 + ((k2 >> 3) & 3) * 16 + (col2 & 15)) * 8 + (k2 & 7)]
                = (unsigned short)bfr(mW2[k2 * 64 + col2]);
        }
    }
    __syncthreads();

    f32x4 z2a[4];
    #pragma unroll
    for (int i = 0; i < 4; ++i) z2a[i] = (f32x4){0.f, 0.f, 0.f, 0.f};
    #pragma unroll
    for (int ks2 = 0; ks2 < 4; ++ks2) {
        u32x4 za = Zh[(w * 4 + ks2) * 64 + l];
        #pragma unroll
        for (int nt2 = 0; nt2 < 4; ++nt2)
            z2a[nt2] = MFMA(za, SW2h[(ks2 * 4 + nt2) * 64 + l], z2a[nt2]);
    }
    float wp[4] = {0.f, 0.f, 0.f, 0.f};
    #pragma unroll
    for (int nt2 = 0; nt2 < 4; ++nt2) {
        int c = nt2 * 16 + c15;
        float bb = mb2[c], w3 = mW3[c];
        #pragma unroll
        for (int r = 0; r < 4; ++r) wp[r] += fmaxf(z2a[nt2][r] + bb, 0.f) * w3;
    }
    #pragma unroll
    for (int r = 0; r < 4; ++r) {
        float p = wp[r];
        #pragma unroll
        for (int m = 1; m <= 8; m <<= 1) p += __shfl_xor(p, m);
        if (c15 == 0) {
            int orow = blockIdx.x * 64 + w * 16 + g * 4 + r;
            out[orow] = p + mb3[0];
        }
    }
}

extern "C" void kernel_launch(void* const* d_in, const int* in_sizes, int n_in,
                              void* d_out, int out_size, void* d_ws, size_t ws_size,
                              hipStream_t stream) {
    const float* X        = (const float*)d_in[0];
    const float* A        = (const float*)d_in[1];
    const int*   v1_idx   = (const int*)d_in[2];
    const int*   v2_idx   = (const int*)d_in[3];
    const int*   seat     = (const int*)d_in[4];
    const float* W0       = (const float*)d_in[5];
    const float* b0       = (const float*)d_in[6];
    const float* g0       = (const float*)d_in[7];
    const float* be0      = (const float*)d_in[8];
    const float* W1       = (const float*)d_in[9];
    const float* b1       = (const float*)d_in[10];
    const float* g1       = (const float*)d_in[11];
    const float* be1      = (const float*)d_in[12];
    const float* W2       = (const float*)d_in[13];
    const float* b2       = (const float*)d_in[14];
    const float* g2       = (const float*)d_in[15];
    const float* be2      = (const float*)d_in[16];
    const float* seat_emb = (const float*)d_in[17];
    const float* mW1      = (const float*)d_in[18];
    const float* mb1      = (const float*)d_in[19];
    const float* mW2      = (const float*)d_in[20];
    const float* mb2      = (const float*)d_in[21];
    const float* mW3      = (const float*)d_in[22];
    const float* mb3      = (const float*)d_in[23];
    const float* rW1      = (const float*)d_in[24];
    const float* rb1      = (const float*)d_in[25];
    const float* rW2      = (const float*)d_in[26];
    const float* rb2      = (const float*)d_in[27];

    const int N = in_sizes[2];           // 16384
    float* out = (float*)d_out;
    float* hws = (float*)d_ws;           // N*416*4 = 27.3MB

    const int spb = 8;
    const int gridA = N / spb;           // 2048
    gcn_mfma<<<gridA, 256, 0, stream>>>(
        X, A, v1_idx, v2_idx, seat,
        W0, b0, g0, be0, W1, b1, g1, be1, W2, b2, g2, be2,
        seat_emb, hws, spb);

    const int gridB = N / 64;            // 256
    head_mfma<<<gridB, 256, 0, stream>>>(
        hws, mW1, mb1, mW2, mb2, mW3, mb3, rW1, rb1, rW2, rb2, out, N);
}

// Round 6
// 487.525 us; speedup vs baseline: 2.2404x; 1.1777x over previous
//
#include <hip/hip_runtime.h>
#include <hip/hip_bf16.h>
#include <math.h>

// ---------------------------------------------------------------------------
// R6 = R5 with the bit_cast compile fix (memcpy extraction of __hip_bfloat162).
//  - hot bf16 packing via v_cvt_pk_bf16_f32 (__float22bfloat162_rn)
//  - conv_epi pair parity compile-time (m2)
//  - launch_bounds(256,3) occupancy push; tripwire = FETCH balloon (R3 spill)
// ---------------------------------------------------------------------------

typedef __bf16 bf16x8 __attribute__((ext_vector_type(8)));
typedef float  f32x4  __attribute__((ext_vector_type(4)));
typedef unsigned int u32x4 __attribute__((ext_vector_type(4)));
typedef unsigned int u32x2 __attribute__((ext_vector_type(2)));

#define DEVINL __device__ __forceinline__

DEVINL unsigned bfr(float x) {             // float -> bf16 bits (RNE) — cold paths
    unsigned u = __float_as_uint(x);
    return (u + 0x7fffu + ((u >> 16) & 1u)) >> 16;
}
DEVINL unsigned pk2(float a, float b) {    // hot path: v_cvt_pk_bf16_f32
    float2 f; f.x = a; f.y = b;
    __hip_bfloat162 h = __float22bfloat162_rn(f);
    unsigned u;
    __builtin_memcpy(&u, &h, sizeof(u));
    return u;
}

DEVINL f32x4 MFMA(u32x4 a, u32x4 b, f32x4 c) {
    return __builtin_amdgcn_mfma_f32_16x16x32_bf16(
        __builtin_bit_cast(bf16x8, a), __builtin_bit_cast(bf16x8, b), c, 0, 0, 0);
}

#define TS 36   // Tlds / Amlds row stride in u32 (pairs of bf16)
#define HS 68   // Hlds row stride in u32

// conv layers 1,2: acc[m2][ut] = (W^T)_tile x H-as-B
DEVINL void conv12(f32x4 (&acc)[2][4], const unsigned* Hlds,
                   const u32x4 (&Wf)[2][4], int g, int c15)
{
    #pragma unroll
    for (int m2 = 0; m2 < 2; ++m2)
        #pragma unroll
        for (int ut = 0; ut < 4; ++ut) acc[m2][ut] = (f32x4){0.f, 0.f, 0.f, 0.f};
    #pragma unroll
    for (int ks = 0; ks < 4; ++ks) {
        u32x4 hb[4];
        #pragma unroll
        for (int ut = 0; ut < 4; ++ut)
            hb[ut] = *(const u32x4*)&Hlds[(ut * 16 + c15) * HS + ks * 16 + g * 4];
        #pragma unroll
        for (int m2 = 0; m2 < 2; ++m2)
            #pragma unroll
            for (int ut = 0; ut < 4; ++ut)
                acc[m2][ut] = MFMA(Wf[m2][ks], hb[ut], acc[m2][ut]);
    }
}

// conv epilogue: acc + bias -> Tlds (row-major bf16 pairs along u)
DEVINL void conv_epi(const f32x4 (&acc)[2][4], unsigned* Tlds, const float* bias,
                     int w, int g, int c15)
{
    #pragma unroll
    for (int m2 = 0; m2 < 2; ++m2) {
        const int chb = (2 * w + m2) * 16;
        f32x4 bb = *(const f32x4*)&bias[chb + g * 4];
        const bool own = (c15 & 1) == m2;
        #pragma unroll
        for (int ut = 0; ut < 4; ++ut)
            #pragma unroll
            for (int r = 0; r < 4; ++r) {
                float val = acc[m2][ut][r] + bb[r];
                float pv  = __shfl_xor(val, 1);
                if (own) {
                    unsigned pair = m2 ? pk2(pv, val) : pk2(val, pv);  // m2 compile-time
                    Tlds[(chb + g * 4 + r) * TS + ut * 8 + (c15 >> 1)] = pair;
                }
            }
    }
}

// mix: macc[mt'] = T2_tile x Amix^T   (vertex = lane c15, wave owns v-tile w)
DEVINL void do_mix(f32x4 (&macc)[8], const unsigned* Tlds, const unsigned* Amlds,
                   int w, int g, int c15)
{
    const int vrow = (w * 16 + c15) * TS + g * 4;
    u32x4 bf0 = *(const u32x4*)&Amlds[vrow];
    u32x4 bf1 = *(const u32x4*)&Amlds[vrow + 16];
    #pragma unroll
    for (int mt = 0; mt < 8; ++mt) {
        const int crow = (mt * 16 + c15) * TS + g * 4;
        u32x4 a0 = *(const u32x4*)&Tlds[crow];
        u32x4 a1 = *(const u32x4*)&Tlds[crow + 16];
        f32x4 a = {0.f, 0.f, 0.f, 0.f};
        a = MFMA(a0, bf0, a);
        a = MFMA(a1, bf1, a);
        macc[mt] = a;
    }
}

// mix epilogue: LN (in-wave) + relu + residual -> Rf; optionally write H to LDS
DEVINL void mix_epi(const f32x4 (&macc)[8], float (&Rf)[8][4], unsigned* Hlds,
                    const float* gam, const float* bet, bool resid, bool writeH,
                    int w, int g, int c15)
{
    float s = 0.f, q = 0.f;
    #pragma unroll
    for (int mt = 0; mt < 8; ++mt)
        #pragma unroll
        for (int r = 0; r < 4; ++r) { float x = macc[mt][r]; s += x; q = fmaf(x, x, q); }
    s += __shfl_xor(s, 16); s += __shfl_xor(s, 32);
    q += __shfl_xor(q, 16); q += __shfl_xor(q, 32);
    const float m   = s * (1.f / 128.f);
    const float var = q * (1.f / 128.f) - m * m;
    const float rs  = rsqrtf(var + 1e-5f);
    const int v = w * 16 + c15;
    #pragma unroll
    for (int mt = 0; mt < 8; ++mt) {
        f32x4 gc = *(const f32x4*)&gam[mt * 16 + g * 4];
        f32x4 bc = *(const f32x4*)&bet[mt * 16 + g * 4];
        #pragma unroll
        for (int r = 0; r < 4; ++r) {
            float val = fmaxf((macc[mt][r] - m) * rs * gc[r] + bc[r], 0.f);
            if (resid) val += Rf[mt][r];
            Rf[mt][r] = val;
        }
        if (writeH) {
            u32x2 pr;
            pr[0] = pk2(Rf[mt][0], Rf[mt][1]);
            pr[1] = pk2(Rf[mt][2], Rf[mt][3]);
            *(u32x2*)&Hlds[v * HS + mt * 8 + g * 2] = pr;
        }
    }
}

// ---------------- kernel A ---------------------------------------------------
__global__ __launch_bounds__(256, 3) void gcn_mfma(
    const float* __restrict__ X, const float* __restrict__ A,
    const int* __restrict__ v1i, const int* __restrict__ v2i, const int* __restrict__ seat,
    const float* __restrict__ W0, const float* __restrict__ b0v,
    const float* __restrict__ g0v, const float* __restrict__ be0,
    const float* __restrict__ W1, const float* __restrict__ b1v,
    const float* __restrict__ g1v, const float* __restrict__ be1,
    const float* __restrict__ W2, const float* __restrict__ b2v,
    const float* __restrict__ g2v, const float* __restrict__ be2,
    const float* __restrict__ semb, float* __restrict__ hws, int spb)
{
    __shared__ unsigned Tlds[128 * TS];   // 18.4KB  T2 row-major [ch][u-pairs]
    __shared__ unsigned Hlds[64 * HS];    // 17.4KB  H  row-major [v][ch-pairs]
    __shared__ unsigned Amlds[64 * TS];   // 9.2KB   Amix row-major [v][u-pairs]
    __shared__ float    PrmL[9][128];     // 4.6KB   bias0..2 | gam0..2 | bet0..2
    __shared__ float    Sm[4][128];       // 2KB     per-wave mean partials

    const int tid = threadIdx.x;
    const int l = tid & 63, w = tid >> 6, g = l >> 4, c15 = l & 15;

    // ---- param tables ----
    if (tid < 128) {
        const int c = tid;
        PrmL[0][c] = b0v[c]; PrmL[1][c] = b1v[c]; PrmL[2][c] = b2v[c];
        PrmL[3][c] = g0v[c]; PrmL[4][c] = g1v[c]; PrmL[5][c] = g2v[c];
        PrmL[6][c] = be0[c]; PrmL[7][c] = be1[c]; PrmL[8][c] = be2[c];
    }
    // ---- Amix row-major bf16 (v<54, u<54 valid, else 0) ----
    for (int p = tid; p < 64 * TS; p += 256) {
        const int v = p / TS, uc = p % TS;
        unsigned val = 0u;
        if (v < 54 && uc < 27) {
            const int u = uc * 2;
            const float a0 = A[v * 54 + u];
            const float a1 = (u + 1 < 54) ? A[v * 54 + u + 1] : 0.f;
            val = pk2(a0, a1);
        }
        Amlds[p] = val;
    }

    // ---- persistent W^T A-fragments (per wave: ch-tiles 2w, 2w+1) ----
    u32x4 W0f[2], W1f[2][4], W2f[2][4];
    #pragma unroll
    for (int m2 = 0; m2 < 2; ++m2) {
        const int ch = (2 * w + m2) * 16 + c15;
        #pragma unroll
        for (int ks = 0; ks < 4; ++ks) {
            unsigned t1[4], t2[4];
            #pragma unroll
            for (int jj = 0; jj < 4; ++jj) {
                const int k = ks * 32 + g * 8 + 2 * jj;
                t1[jj] = pk2(W1[k * 128 + ch], W1[(k + 1) * 128 + ch]);
                t2[jj] = pk2(W2[k * 128 + ch], W2[(k + 1) * 128 + ch]);
            }
            W1f[m2][ks] = (u32x4){t1[0], t1[1], t1[2], t1[3]};
            W2f[m2][ks] = (u32x4){t2[0], t2[1], t2[2], t2[3]};
        }
        unsigned t0[4];
        #pragma unroll
        for (int jj = 0; jj < 4; ++jj) {
            const int k = g * 8 + 2 * jj;
            t0[jj] = (g < 2) ? pk2(W0[k * 128 + ch], W0[(k + 1) * 128 + ch]) : 0u;
        }
        W0f[m2] = (u32x4){t0[0], t0[1], t0[2], t0[3]};
    }
    __syncthreads();

    float Rf[8][4];      // fp32 residual H: this lane's vertex, channels mt*16+g*4+r
    f32x4 acc[2][4];     // conv accumulators
    f32x4 macc[8];       // mix accumulators

    #pragma unroll 1
    for (int it = 0; it < spb; ++it) {
        const int n = blockIdx.x + gridDim.x * it;

        // ---- conv0: T2 = W0^T * X2 (K=16 zero-padded to 32) ----
        #pragma unroll
        for (int m2 = 0; m2 < 2; ++m2)
            #pragma unroll
            for (int ut = 0; ut < 4; ++ut) acc[m2][ut] = (f32x4){0.f, 0.f, 0.f, 0.f};
        #pragma unroll
        for (int ut = 0; ut < 4; ++ut) {
            const int u = ut * 16 + c15;
            u32x4 xb = (u32x4){0u, 0u, 0u, 0u};
            if (g < 2 && u < 54) {
                const f32x4* xp = (const f32x4*)(X + (size_t)n * 864 + u * 16 + g * 8);
                f32x4 f0 = xp[0], f1 = xp[1];
                xb = (u32x4){pk2(f0[0], f0[1]), pk2(f0[2], f0[3]),
                             pk2(f1[0], f1[1]), pk2(f1[2], f1[3])};
            }
            #pragma unroll
            for (int m2 = 0; m2 < 2; ++m2)
                acc[m2][ut] = MFMA(W0f[m2], xb, acc[m2][ut]);
        }
        conv_epi(acc, Tlds, &PrmL[0][0], w, g, c15);
        __syncthreads();
        do_mix(macc, Tlds, Amlds, w, g, c15);
        mix_epi(macc, Rf, Hlds, &PrmL[3][0], &PrmL[6][0], false, true, w, g, c15);
        __syncthreads();

        // ---- layer 1 ----
        conv12(acc, Hlds, W1f, g, c15);
        conv_epi(acc, Tlds, &PrmL[1][0], w, g, c15);
        __syncthreads();
        do_mix(macc, Tlds, Amlds, w, g, c15);
        mix_epi(macc, Rf, Hlds, &PrmL[4][0], &PrmL[7][0], true, true, w, g, c15);
        __syncthreads();

        // ---- layer 2 ----
        conv12(acc, Hlds, W2f, g, c15);
        conv_epi(acc, Tlds, &PrmL[2][0], w, g, c15);
        __syncthreads();
        do_mix(macc, Tlds, Amlds, w, g, c15);
        mix_epi(macc, Rf, Hlds, &PrmL[5][0], &PrmL[8][0], true, false, w, g, c15);

        // ---- head features -> hws [N][416] ----
        const int v1 = v1i[n], v2 = v2i[n];
        int st = seat[n];
        st = st < 0 ? 0 : (st > 3 ? 3 : st);
        float* hr = hws + (size_t)n * 416;
        const int v = w * 16 + c15;

        // v1/v2 gather: the 4 g-lanes of the matching vertex write its 128 chs
        if (v == v1 || v == v2) {
            #pragma unroll
            for (int mt = 0; mt < 8; ++mt) {
                f32x4 t;
                #pragma unroll
                for (int r = 0; r < 4; ++r) t[r] = Rf[mt][r];
                if (v == v1) *(f32x4*)&hr[mt * 16 + g * 4] = t;
                if (v == v2) *(f32x4*)&hr[128 + mt * 16 + g * 4] = t;
            }
        }

        // mean over verts: multi-value butterfly over c15 (30 shfl), then Sm
        {
            const bool vok = (v < 54);
            float t16[16];
            #pragma unroll
            for (int jj = 0; jj < 16; ++jj) {
                float a = vok ? Rf[(2*jj) >> 2][(2*jj) & 3] : 0.f;
                float b = vok ? Rf[(2*jj+1) >> 2][(2*jj+1) & 3] : 0.f;
                float mine = (c15 & 1) ? b : a;
                float oth  = (c15 & 1) ? a : b;
                t16[jj] = mine + __shfl_xor(oth, 1);
            }
            float t8[8];
            #pragma unroll
            for (int jj = 0; jj < 8; ++jj) {
                float a = t16[2*jj], b = t16[2*jj+1];
                float mine = (c15 & 2) ? b : a;
                float oth  = (c15 & 2) ? a : b;
                t8[jj] = mine + __shfl_xor(oth, 2);
            }
            float t4[4];
            #pragma unroll
            for (int jj = 0; jj < 4; ++jj) {
                float a = t8[2*jj], b = t8[2*jj+1];
                float mine = (c15 & 4) ? b : a;
                float oth  = (c15 & 4) ? a : b;
                t4[jj] = mine + __shfl_xor(oth, 4);
            }
            float t2a[2];
            #pragma unroll
            for (int jj = 0; jj < 2; ++jj) {
                float a = t4[2*jj], b = t4[2*jj+1];
                float mine = (c15 & 8) ? b : a;
                float oth  = (c15 & 8) ? a : b;
                t2a[jj] = mine + __shfl_xor(oth, 8);
            }
            const int ch1 = (c15 >> 2) * 16 + g * 4 + (c15 & 3);
            Sm[w][ch1]      = t2a[0];
            Sm[w][ch1 + 64] = t2a[1];
        }
        __syncthreads();
        if (tid < 128) {
            const float mn = (Sm[0][tid] + Sm[1][tid] + Sm[2][tid] + Sm[3][tid]) * (1.f / 54.f);
            hr[256 + tid] = mn;
        }
        if (tid < 8)       hr[384 + tid] = semb[st * 8 + tid];
        else if (tid < 32) hr[384 + tid] = 0.f;
    }
}

// ---------------- kernel B: batched head -------------------------------------
__global__ __launch_bounds__(256, 2) void head_mfma(
    const float* __restrict__ hws,
    const float* __restrict__ mW1, const float* __restrict__ mb1,
    const float* __restrict__ mW2, const float* __restrict__ mb2,
    const float* __restrict__ mW3, const float* __restrict__ mb3,
    const float* __restrict__ rW1, const float* __restrict__ rb1,
    const float* __restrict__ rW2, const float* __restrict__ rb2,
    float* __restrict__ out, int N)
{
    __shared__ u32x4 pool[2048];          // 32KB
    u32x4* SW1h = pool;
    u32x4* SW1l = pool + 512;
    u32x4* SR1h = pool + 1024;
    u32x4* Zh   = pool;
    u32x4* SW2h = pool + 1024;

    const int tid = threadIdx.x, l = tid & 63, w = tid >> 6, g = l >> 4, c15 = l & 15;
    const int row = blockIdx.x * 64 + w * 16 + c15;

    f32x4 z1[8], rr[4];
    #pragma unroll
    for (int i = 0; i < 8; ++i) z1[i] = (f32x4){0.f, 0.f, 0.f, 0.f};
    #pragma unroll
    for (int i = 0; i < 4; ++i) rr[i] = (f32x4){0.f, 0.f, 0.f, 0.f};

    for (int ks = 0; ks < 13; ++ks) {
        {
            int col = tid & 127, kbase = (tid >> 7) * 16;
            unsigned short* ph = (unsigned short*)SW1h;
            unsigned short* pl = (unsigned short*)SW1l;
            #pragma unroll
            for (int kk = 0; kk < 16; ++kk) {
                int kloc = kbase + kk, k = ks * 32 + kloc;
                float wv = (k < 392) ? mW1[k * 128 + col] : 0.f;
                unsigned hi = bfr(wv);
                float lof = wv - __uint_as_float(hi << 16);
                int idx = ((col >> 4) * 64 + ((kloc >> 3) & 3) * 16 + (col & 15)) * 8 + (kloc & 7);
                ph[idx] = (unsigned short)hi;
                pl[idx] = (unsigned short)bfr(lof);
            }
            int col2 = tid & 63, kb2 = (tid >> 6) * 8;
            unsigned short* pr = (unsigned short*)SR1h;
            #pragma unroll
            for (int kk = 0; kk < 8; ++kk) {
                int kloc = kb2 + kk, k = ks * 32 + kloc;
                float wv = (k < 392) ? rW1[k * 64 + col2] : 0.f;
                pr[((col2 >> 4) * 64 + ((kloc >> 3) & 3) * 16 + (col2 & 15)) * 8 + (kloc & 7)]
                    = (unsigned short)bfr(wv);
            }
        }
        __syncthreads();
        const float* hp = hws + (size_t)row * 416 + ks * 32 + g * 8;
        f32x4 f0 = *(const f32x4*)hp, f1 = *(const f32x4*)(hp + 4);
        float vv[8] = {f0[0], f0[1], f0[2], f0[3], f1[0], f1[1], f1[2], f1[3]};
        unsigned th[4], tl[4];
        #pragma unroll
        for (int jj = 0; jj < 4; ++jj) {
            unsigned ha = bfr(vv[2 * jj]), hb = bfr(vv[2 * jj + 1]);
            th[jj] = ha | (hb << 16);
            tl[jj] = pk2(vv[2 * jj] - __uint_as_float(ha << 16),
                         vv[2 * jj + 1] - __uint_as_float(hb << 16));
        }
        u32x4 ah = (u32x4){th[0], th[1], th[2], th[3]};
        u32x4 al = (u32x4){tl[0], tl[1], tl[2], tl[3]};
        #pragma unroll
        for (int nt = 0; nt < 8; ++nt) {
            u32x4 bh = SW1h[nt * 64 + l], bl = SW1l[nt * 64 + l];
            f32x4 a = z1[nt];
            a = MFMA(ah, bh, a); a = MFMA(ah, bl, a); a = MFMA(al, bh, a);
            z1[nt] = a;
        }
        #pragma unroll
        for (int nt = 0; nt < 4; ++nt) rr[nt] = MFMA(ah, SR1h[nt * 64 + l], rr[nt]);
        __syncthreads();
    }

    float rp[4] = {0.f, 0.f, 0.f, 0.f};
    #pragma unroll
    for (int nt = 0; nt < 4; ++nt) {
        int c = nt * 16 + c15;
        float rb = rb1[c], rw = rW2[c];
        #pragma unroll
        for (int r = 0; r < 4; ++r) rp[r] += fmaxf(rr[nt][r] + rb, 0.f) * rw;
    }
    #pragma unroll
    for (int r = 0; r < 4; ++r) {
        float p = rp[r];
        #pragma unroll
        for (int m = 1; m <= 8; m <<= 1) p += __shfl_xor(p, m);
        if (c15 == 0) {
            int orow = blockIdx.x * 64 + w * 16 + g * 4 + r;
            out[N + orow] = 1.f / (1.f + expf(-(p + rb2[0])));
        }
    }

    {
        unsigned short* zp = (unsigned short*)Zh;
        #pragma unroll
        for (int nt = 0; nt < 8; ++nt) {
            int c = nt * 16 + c15;
            float bb = mb1[c];
            #pragma unroll
            for (int r = 0; r < 4; ++r) {
                float v = fmaxf(z1[nt][r] + bb, 0.f);
                int lanep = ((nt * 2 + (c15 >> 3)) & 3) * 16 + g * 4 + r;
                zp[((w * 4 + (nt >> 1)) * 64 + lanep) * 8 + (c15 & 7)] = (unsigned short)bfr(v);
            }
        }
        unsigned short* p2 = (unsigned short*)SW2h;
        int col2 = tid & 63, kb = (tid >> 6) * 32;
        #pragma unroll
        for (int kk = 0; kk < 32; ++kk) {
            int k2 = kb + kk;
            p2[(((k2 >> 5) * 4 + (col2 >> 4)) * 64 + ((k2 >> 3) & 3) * 16 + (col2 & 15)) * 8 + (k2 & 7)]
                = (unsigned short)bfr(mW2[k2 * 64 + col2]);
        }
    }
    __syncthreads();

    f32x4 z2a[4];
    #pragma unroll
    for (int i = 0; i < 4; ++i) z2a[i] = (f32x4){0.f, 0.f, 0.f, 0.f};
    #pragma unroll
    for (int ks2 = 0; ks2 < 4; ++ks2) {
        u32x4 za = Zh[(w * 4 + ks2) * 64 + l];
        #pragma unroll
        for (int nt2 = 0; nt2 < 4; ++nt2)
            z2a[nt2] = MFMA(za, SW2h[(ks2 * 4 + nt2) * 64 + l], z2a[nt2]);
    }
    float wp[4] = {0.f, 0.f, 0.f, 0.f};
    #pragma unroll
    for (int nt2 = 0; nt2 < 4; ++nt2) {
        int c = nt2 * 16 + c15;
        float bb = mb2[c], w3 = mW3[c];
        #pragma unroll
        for (int r = 0; r < 4; ++r) wp[r] += fmaxf(z2a[nt2][r] + bb, 0.f) * w3;
    }
    #pragma unroll
    for (int r = 0; r < 4; ++r) {
        float p = wp[r];
        #pragma unroll
        for (int m = 1; m <= 8; m <<= 1) p += __shfl_xor(p, m);
        if (c15 == 0) {
            int orow = blockIdx.x * 64 + w * 16 + g * 4 + r;
            out[orow] = p + mb3[0];
        }
    }
}

extern "C" void kernel_launch(void* const* d_in, const int* in_sizes, int n_in,
                              void* d_out, int out_size, void* d_ws, size_t ws_size,
                              hipStream_t stream) {
    const float* X        = (const float*)d_in[0];
    const float* A        = (const float*)d_in[1];
    const int*   v1_idx   = (const int*)d_in[2];
    const int*   v2_idx   = (const int*)d_in[3];
    const int*   seat     = (const int*)d_in[4];
    const float* W0       = (const float*)d_in[5];
    const float* b0       = (const float*)d_in[6];
    const float* g0       = (const float*)d_in[7];
    const float* be0      = (const float*)d_in[8];
    const float* W1       = (const float*)d_in[9];
    const float* b1       = (const float*)d_in[10];
    const float* g1       = (const float*)d_in[11];
    const float* be1      = (const float*)d_in[12];
    const float* W2       = (const float*)d_in[13];
    const float* b2       = (const float*)d_in[14];
    const float* g2       = (const float*)d_in[15];
    const float* be2      = (const float*)d_in[16];
    const float* seat_emb = (const float*)d_in[17];
    const float* mW1      = (const float*)d_in[18];
    const float* mb1      = (const float*)d_in[19];
    const float* mW2      = (const float*)d_in[20];
    const float* mb2      = (const float*)d_in[21];
    const float* mW3      = (const float*)d_in[22];
    const float* mb3      = (const float*)d_in[23];
    const float* rW1      = (const float*)d_in[24];
    const float* rb1      = (const float*)d_in[25];
    const float* rW2      = (const float*)d_in[26];
    const float* rb2      = (const float*)d_in[27];

    const int N = in_sizes[2];           // 16384
    float* out = (float*)d_out;
    float* hws = (float*)d_ws;           // N*416*4 = 27.3MB

    const int spb = 8;
    const int gridA = N / spb;           // 2048
    gcn_mfma<<<gridA, 256, 0, stream>>>(
        X, A, v1_idx, v2_idx, seat,
        W0, b0, g0, be0, W1, b1, g1, be1, W2, b2, g2, be2,
        seat_emb, hws, spb);

    const int gridB = N / 64;            // 256
    head_mfma<<<gridB, 256, 0, stream>>>(
        hws, mW1, mb1, mW2, mb2, mW3, mb3, rW1, rb1, rW2, rb2, out, N);
}

// Round 7
// 443.836 us; speedup vs baseline: 2.4609x; 1.0984x over previous
//
#include <hip/hip_runtime.h>
#include <hip/hip_bf16.h>
#include <math.h>

// ---------------------------------------------------------------------------
// R7: two levers vs R6:
//  A) kernel A: conv acc + mix macc unified into ONE f32x4 rg[8] (disjoint
//     live ranges; R6's spill at (256,3) showed the compiler didn't coalesce).
//     Target: fit 170 regs/wave -> 3 blocks/CU with ZERO scratch.
//  B) head weights pre-converted ONCE into frag-ordered bf16 (hi/lo) in d_ws
//     by a tiny init kernel; kernel B reads B-operands from global (L2) —
//     kills per-block split recomputation + LDS staging + 24 barriers.
//     hws stride 416 -> 400 so total ws use (26.5MB) stays under proven 27.3MB.
// ---------------------------------------------------------------------------

typedef __bf16 bf16x8 __attribute__((ext_vector_type(8)));
typedef float  f32x4  __attribute__((ext_vector_type(4)));
typedef unsigned int u32x4 __attribute__((ext_vector_type(4)));
typedef unsigned int u32x2 __attribute__((ext_vector_type(2)));

#define DEVINL __device__ __forceinline__
#define HROW 400   // hws row stride (floats); cols 392..399 zero-padded

DEVINL unsigned bfr(float x) {             // float -> bf16 bits (RNE)
    unsigned u = __float_as_uint(x);
    return (u + 0x7fffu + ((u >> 16) & 1u)) >> 16;
}
DEVINL unsigned pk2(float a, float b) {    // v_cvt_pk_bf16_f32
    float2 f; f.x = a; f.y = b;
    __hip_bfloat162 h = __float22bfloat162_rn(f);
    unsigned u;
    __builtin_memcpy(&u, &h, sizeof(u));
    return u;
}

DEVINL f32x4 MFMA(u32x4 a, u32x4 b, f32x4 c) {
    return __builtin_amdgcn_mfma_f32_16x16x32_bf16(
        __builtin_bit_cast(bf16x8, a), __builtin_bit_cast(bf16x8, b), c, 0, 0, 0);
}

#define TS 36   // Tlds / Amlds row stride in u32 (pairs of bf16)
#define HS 68   // Hlds row stride in u32

// conv layers 1,2: rg[m2*4+ut] = (W^T)_tile x H-as-B
DEVINL void conv12(f32x4 (&rg)[8], const unsigned* Hlds,
                   const u32x4 (&Wf)[2][4], int g, int c15)
{
    #pragma unroll
    for (int i = 0; i < 8; ++i) rg[i] = (f32x4){0.f, 0.f, 0.f, 0.f};
    #pragma unroll
    for (int ks = 0; ks < 4; ++ks) {
        u32x4 hb[4];
        #pragma unroll
        for (int ut = 0; ut < 4; ++ut)
            hb[ut] = *(const u32x4*)&Hlds[(ut * 16 + c15) * HS + ks * 16 + g * 4];
        #pragma unroll
        for (int m2 = 0; m2 < 2; ++m2)
            #pragma unroll
            for (int ut = 0; ut < 4; ++ut)
                rg[m2 * 4 + ut] = MFMA(Wf[m2][ks], hb[ut], rg[m2 * 4 + ut]);
    }
}

// conv epilogue: rg + bias -> Tlds (row-major bf16 pairs along u)
DEVINL void conv_epi(const f32x4 (&rg)[8], unsigned* Tlds, const float* bias,
                     int w, int g, int c15)
{
    #pragma unroll
    for (int m2 = 0; m2 < 2; ++m2) {
        const int chb = (2 * w + m2) * 16;
        f32x4 bb = *(const f32x4*)&bias[chb + g * 4];
        const bool own = (c15 & 1) == m2;
        #pragma unroll
        for (int ut = 0; ut < 4; ++ut)
            #pragma unroll
            for (int r = 0; r < 4; ++r) {
                float val = rg[m2 * 4 + ut][r] + bb[r];
                float pv  = __shfl_xor(val, 1);
                if (own) {
                    unsigned pair = m2 ? pk2(pv, val) : pk2(val, pv);
                    Tlds[(chb + g * 4 + r) * TS + ut * 8 + (c15 >> 1)] = pair;
                }
            }
    }
}

// mix: rg[mt] = T2_tile x Amix^T   (vertex = lane c15, wave owns v-tile w)
DEVINL void do_mix(f32x4 (&rg)[8], const unsigned* Tlds, const unsigned* Amlds,
                   int w, int g, int c15)
{
    const int vrow = (w * 16 + c15) * TS + g * 4;
    u32x4 bf0 = *(const u32x4*)&Amlds[vrow];
    u32x4 bf1 = *(const u32x4*)&Amlds[vrow + 16];
    #pragma unroll
    for (int mt = 0; mt < 8; ++mt) {
        const int crow = (mt * 16 + c15) * TS + g * 4;
        u32x4 a0 = *(const u32x4*)&Tlds[crow];
        u32x4 a1 = *(const u32x4*)&Tlds[crow + 16];
        f32x4 a = {0.f, 0.f, 0.f, 0.f};
        a = MFMA(a0, bf0, a);
        a = MFMA(a1, bf1, a);
        rg[mt] = a;
    }
}

// mix epilogue: LN (in-wave) + relu + residual -> Rf; optionally write H to LDS
DEVINL void mix_epi(const f32x4 (&rg)[8], float (&Rf)[8][4], unsigned* Hlds,
                    const float* gam, const float* bet, bool resid, bool writeH,
                    int w, int g, int c15)
{
    float s = 0.f, q = 0.f;
    #pragma unroll
    for (int mt = 0; mt < 8; ++mt)
        #pragma unroll
        for (int r = 0; r < 4; ++r) { float x = rg[mt][r]; s += x; q = fmaf(x, x, q); }
    s += __shfl_xor(s, 16); s += __shfl_xor(s, 32);
    q += __shfl_xor(q, 16); q += __shfl_xor(q, 32);
    const float m   = s * (1.f / 128.f);
    const float var = q * (1.f / 128.f) - m * m;
    const float rs  = rsqrtf(var + 1e-5f);
    const int v = w * 16 + c15;
    #pragma unroll
    for (int mt = 0; mt < 8; ++mt) {
        f32x4 gc = *(const f32x4*)&gam[mt * 16 + g * 4];
        f32x4 bc = *(const f32x4*)&bet[mt * 16 + g * 4];
        #pragma unroll
        for (int r = 0; r < 4; ++r) {
            float val = fmaxf((rg[mt][r] - m) * rs * gc[r] + bc[r], 0.f);
            if (resid) val += Rf[mt][r];
            Rf[mt][r] = val;
        }
        if (writeH) {
            u32x2 pr;
            pr[0] = pk2(Rf[mt][0], Rf[mt][1]);
            pr[1] = pk2(Rf[mt][2], Rf[mt][3]);
            *(u32x2*)&Hlds[v * HS + mt * 8 + g * 2] = pr;
        }
    }
}

// ---------------- kernel A ---------------------------------------------------
__global__ __launch_bounds__(256, 3) void gcn_mfma(
    const float* __restrict__ X, const float* __restrict__ A,
    const int* __restrict__ v1i, const int* __restrict__ v2i, const int* __restrict__ seat,
    const float* __restrict__ W0, const float* __restrict__ b0v,
    const float* __restrict__ g0v, const float* __restrict__ be0,
    const float* __restrict__ W1, const float* __restrict__ b1v,
    const float* __restrict__ g1v, const float* __restrict__ be1,
    const float* __restrict__ W2, const float* __restrict__ b2v,
    const float* __restrict__ g2v, const float* __restrict__ be2,
    const float* __restrict__ semb, float* __restrict__ hws, int spb)
{
    __shared__ unsigned Tlds[128 * TS];   // 18.4KB
    __shared__ unsigned Hlds[64 * HS];    // 17.4KB
    __shared__ unsigned Amlds[64 * TS];   // 9.2KB
    __shared__ float    PrmL[9][128];     // 4.6KB
    __shared__ float    Sm[4][128];       // 2KB

    const int tid = threadIdx.x;
    const int l = tid & 63, w = tid >> 6, g = l >> 4, c15 = l & 15;

    if (tid < 128) {
        const int c = tid;
        PrmL[0][c] = b0v[c]; PrmL[1][c] = b1v[c]; PrmL[2][c] = b2v[c];
        PrmL[3][c] = g0v[c]; PrmL[4][c] = g1v[c]; PrmL[5][c] = g2v[c];
        PrmL[6][c] = be0[c]; PrmL[7][c] = be1[c]; PrmL[8][c] = be2[c];
    }
    for (int p = tid; p < 64 * TS; p += 256) {
        const int v = p / TS, uc = p % TS;
        unsigned val = 0u;
        if (v < 54 && uc < 27) {
            const int u = uc * 2;
            const float a0 = A[v * 54 + u];
            const float a1 = (u + 1 < 54) ? A[v * 54 + u + 1] : 0.f;
            val = pk2(a0, a1);
        }
        Amlds[p] = val;
    }

    u32x4 W0f[2], W1f[2][4], W2f[2][4];
    #pragma unroll
    for (int m2 = 0; m2 < 2; ++m2) {
        const int ch = (2 * w + m2) * 16 + c15;
        #pragma unroll
        for (int ks = 0; ks < 4; ++ks) {
            unsigned t1[4], t2[4];
            #pragma unroll
            for (int jj = 0; jj < 4; ++jj) {
                const int k = ks * 32 + g * 8 + 2 * jj;
                t1[jj] = pk2(W1[k * 128 + ch], W1[(k + 1) * 128 + ch]);
                t2[jj] = pk2(W2[k * 128 + ch], W2[(k + 1) * 128 + ch]);
            }
            W1f[m2][ks] = (u32x4){t1[0], t1[1], t1[2], t1[3]};
            W2f[m2][ks] = (u32x4){t2[0], t2[1], t2[2], t2[3]};
        }
        unsigned t0[4];
        #pragma unroll
        for (int jj = 0; jj < 4; ++jj) {
            const int k = g * 8 + 2 * jj;
            t0[jj] = (g < 2) ? pk2(W0[k * 128 + ch], W0[(k + 1) * 128 + ch]) : 0u;
        }
        W0f[m2] = (u32x4){t0[0], t0[1], t0[2], t0[3]};
    }
    __syncthreads();

    float Rf[8][4];
    f32x4 rg[8];     // UNIFIED conv/mix accumulators (disjoint live ranges)

    #pragma unroll 1
    for (int it = 0; it < spb; ++it) {
        const int n = blockIdx.x + gridDim.x * it;

        // ---- conv0 ----
        #pragma unroll
        for (int i = 0; i < 8; ++i) rg[i] = (f32x4){0.f, 0.f, 0.f, 0.f};
        #pragma unroll
        for (int ut = 0; ut < 4; ++ut) {
            const int u = ut * 16 + c15;
            u32x4 xb = (u32x4){0u, 0u, 0u, 0u};
            if (g < 2 && u < 54) {
                const f32x4* xp = (const f32x4*)(X + (size_t)n * 864 + u * 16 + g * 8);
                f32x4 f0 = xp[0], f1 = xp[1];
                xb = (u32x4){pk2(f0[0], f0[1]), pk2(f0[2], f0[3]),
                             pk2(f1[0], f1[1]), pk2(f1[2], f1[3])};
            }
            #pragma unroll
            for (int m2 = 0; m2 < 2; ++m2)
                rg[m2 * 4 + ut] = MFMA(W0f[m2], xb, rg[m2 * 4 + ut]);
        }
        conv_epi(rg, Tlds, &PrmL[0][0], w, g, c15);
        __syncthreads();
        do_mix(rg, Tlds, Amlds, w, g, c15);
        mix_epi(rg, Rf, Hlds, &PrmL[3][0], &PrmL[6][0], false, true, w, g, c15);
        __syncthreads();

        // ---- layer 1 ----
        conv12(rg, Hlds, W1f, g, c15);
        conv_epi(rg, Tlds, &PrmL[1][0], w, g, c15);
        __syncthreads();
        do_mix(rg, Tlds, Amlds, w, g, c15);
        mix_epi(rg, Rf, Hlds, &PrmL[4][0], &PrmL[7][0], true, true, w, g, c15);
        __syncthreads();

        // ---- layer 2 ----
        conv12(rg, Hlds, W2f, g, c15);
        conv_epi(rg, Tlds, &PrmL[2][0], w, g, c15);
        __syncthreads();
        do_mix(rg, Tlds, Amlds, w, g, c15);
        mix_epi(rg, Rf, Hlds, &PrmL[5][0], &PrmL[8][0], true, false, w, g, c15);

        // ---- head features -> hws [N][HROW] ----
        const int v1 = v1i[n], v2 = v2i[n];
        int st = seat[n];
        st = st < 0 ? 0 : (st > 3 ? 3 : st);
        float* hr = hws + (size_t)n * HROW;
        const int v = w * 16 + c15;

        if (v == v1 || v == v2) {
            #pragma unroll
            for (int mt = 0; mt < 8; ++mt) {
                f32x4 t;
                #pragma unroll
                for (int r = 0; r < 4; ++r) t[r] = Rf[mt][r];
                if (v == v1) *(f32x4*)&hr[mt * 16 + g * 4] = t;
                if (v == v2) *(f32x4*)&hr[128 + mt * 16 + g * 4] = t;
            }
        }

        {
            const bool vok = (v < 54);
            float t16[16];
            #pragma unroll
            for (int jj = 0; jj < 16; ++jj) {
                float a = vok ? Rf[(2*jj) >> 2][(2*jj) & 3] : 0.f;
                float b = vok ? Rf[(2*jj+1) >> 2][(2*jj+1) & 3] : 0.f;
                float mine = (c15 & 1) ? b : a;
                float oth  = (c15 & 1) ? a : b;
                t16[jj] = mine + __shfl_xor(oth, 1);
            }
            float t8[8];
            #pragma unroll
            for (int jj = 0; jj < 8; ++jj) {
                float a = t16[2*jj], b = t16[2*jj+1];
                float mine = (c15 & 2) ? b : a;
                float oth  = (c15 & 2) ? a : b;
                t8[jj] = mine + __shfl_xor(oth, 2);
            }
            float t4[4];
            #pragma unroll
            for (int jj = 0; jj < 4; ++jj) {
                float a = t8[2*jj], b = t8[2*jj+1];
                float mine = (c15 & 4) ? b : a;
                float oth  = (c15 & 4) ? a : b;
                t4[jj] = mine + __shfl_xor(oth, 4);
            }
            float t2a[2];
            #pragma unroll
            for (int jj = 0; jj < 2; ++jj) {
                float a = t4[2*jj], b = t4[2*jj+1];
                float mine = (c15 & 8) ? b : a;
                float oth  = (c15 & 8) ? a : b;
                t2a[jj] = mine + __shfl_xor(oth, 8);
            }
            const int ch1 = (c15 >> 2) * 16 + g * 4 + (c15 & 3);
            Sm[w][ch1]      = t2a[0];
            Sm[w][ch1 + 64] = t2a[1];
        }
        __syncthreads();
        if (tid < 128) {
            const float mn = (Sm[0][tid] + Sm[1][tid] + Sm[2][tid] + Sm[3][tid]) * (1.f / 54.f);
            hr[256 + tid] = mn;
        }
        if (tid < 8)       hr[384 + tid] = semb[st * 8 + tid];
        else if (tid < 16) hr[384 + tid] = 0.f;   // pad cols 392..399
    }
}

// ---------------- head weight frag init (runs once per launch, ~us) ----------
__global__ void head_frag_init(const float* __restrict__ mW1,
                               const float* __restrict__ rW1,
                               const float* __restrict__ mW2,
                               unsigned* __restrict__ W1h, unsigned* __restrict__ W1l,
                               unsigned* __restrict__ R1h, unsigned* __restrict__ W2h)
{
    const int t = blockIdx.x * 256 + threadIdx.x;
    // W1h/W1l: 13ks x 128col x 4g x 4j = 26624 u32 each
    if (t < 13 * 128 * 16) {
        const int j = t & 3, g = (t >> 2) & 3, col = (t >> 4) & 127, ks = t >> 11;
        const int k = ks * 32 + g * 8 + 2 * j;
        const float w0 = (k < 392)     ? mW1[k * 128 + col]       : 0.f;
        const float w1 = (k + 1 < 392) ? mW1[(k + 1) * 128 + col] : 0.f;
        const unsigned h0 = bfr(w0), h1 = bfr(w1);
        const float l0 = w0 - __uint_as_float(h0 << 16);
        const float l1 = w1 - __uint_as_float(h1 << 16);
        const int idx = ((ks * 8 + (col >> 4)) * 64 + g * 16 + (col & 15)) * 4 + j;
        W1h[idx] = h0 | (h1 << 16);
        W1l[idx] = pk2(l0, l1);
    }
    // R1h: 13ks x 64col x 4g x 4j = 13312 u32
    if (t < 13 * 64 * 16) {
        const int j = t & 3, g = (t >> 2) & 3, col = (t >> 4) & 63, ks = t >> 10;
        const int k = ks * 32 + g * 8 + 2 * j;
        const float w0 = (k < 392)     ? rW1[k * 64 + col]       : 0.f;
        const float w1 = (k + 1 < 392) ? rW1[(k + 1) * 64 + col] : 0.f;
        const int idx = ((ks * 4 + (col >> 4)) * 64 + g * 16 + (col & 15)) * 4 + j;
        R1h[idx] = pk2(w0, w1);
    }
    // W2h: 4ks2 x 64col x 4g x 4j = 4096 u32
    if (t < 4 * 64 * 16) {
        const int j = t & 3, g = (t >> 2) & 3, col = (t >> 4) & 63, ks2 = t >> 10;
        const int k = ks2 * 32 + g * 8 + 2 * j;
        const int idx = ((ks2 * 4 + (col >> 4)) * 64 + g * 16 + (col & 15)) * 4 + j;
        W2h[idx] = pk2(mW2[k * 64 + col], mW2[(k + 1) * 64 + col]);
    }
}

// ---------------- kernel B: batched head, weights from global frags ----------
__global__ __launch_bounds__(256, 2) void head_mfma(
    const float* __restrict__ hws,
    const unsigned* __restrict__ W1hG, const unsigned* __restrict__ W1lG,
    const unsigned* __restrict__ R1hG, const unsigned* __restrict__ W2hG,
    const float* __restrict__ mb1, const float* __restrict__ mb2,
    const float* __restrict__ mW3, const float* __restrict__ mb3,
    const float* __restrict__ rb1, const float* __restrict__ rW2,
    const float* __restrict__ rb2,
    float* __restrict__ out, int N)
{
    __shared__ u32x4 Zh[16 * 64];         // 16KB

    const int tid = threadIdx.x, l = tid & 63, w = tid >> 6, g = l >> 4, c15 = l & 15;
    const int row = blockIdx.x * 64 + w * 16 + c15;

    const u32x4* W1h4 = (const u32x4*)W1hG;
    const u32x4* W1l4 = (const u32x4*)W1lG;
    const u32x4* R1h4 = (const u32x4*)R1hG;
    const u32x4* W2h4 = (const u32x4*)W2hG;

    f32x4 z1[8], rr[4];
    #pragma unroll
    for (int i = 0; i < 8; ++i) z1[i] = (f32x4){0.f, 0.f, 0.f, 0.f};
    #pragma unroll
    for (int i = 0; i < 4; ++i) rr[i] = (f32x4){0.f, 0.f, 0.f, 0.f};

    #pragma unroll 1
    for (int ks = 0; ks < 13; ++ks) {
        const float* hp = hws + (size_t)row * HROW + ks * 32 + g * 8;
        f32x4 f0 = *(const f32x4*)hp, f1 = *(const f32x4*)(hp + 4);
        float vv[8] = {f0[0], f0[1], f0[2], f0[3], f1[0], f1[1], f1[2], f1[3]};
        unsigned th[4], tl[4];
        #pragma unroll
        for (int jj = 0; jj < 4; ++jj) {
            unsigned ha = bfr(vv[2 * jj]), hb = bfr(vv[2 * jj + 1]);
            th[jj] = ha | (hb << 16);
            tl[jj] = pk2(vv[2 * jj] - __uint_as_float(ha << 16),
                         vv[2 * jj + 1] - __uint_as_float(hb << 16));
        }
        u32x4 ah = (u32x4){th[0], th[1], th[2], th[3]};
        u32x4 al = (u32x4){tl[0], tl[1], tl[2], tl[3]};
        #pragma unroll
        for (int nt = 0; nt < 8; ++nt) {
            u32x4 bh = W1h4[(ks * 8 + nt) * 64 + l];
            u32x4 bl = W1l4[(ks * 8 + nt) * 64 + l];
            f32x4 a = z1[nt];
            a = MFMA(ah, bh, a); a = MFMA(ah, bl, a); a = MFMA(al, bh, a);
            z1[nt] = a;
        }
        #pragma unroll
        for (int nt = 0; nt < 4; ++nt)
            rr[nt] = MFMA(ah, R1h4[(ks * 4 + nt) * 64 + l], rr[nt]);
    }

    // rank head
    float rp[4] = {0.f, 0.f, 0.f, 0.f};
    #pragma unroll
    for (int nt = 0; nt < 4; ++nt) {
        int c = nt * 16 + c15;
        float rb = rb1[c], rw = rW2[c];
        #pragma unroll
        for (int r = 0; r < 4; ++r) rp[r] += fmaxf(rr[nt][r] + rb, 0.f) * rw;
    }
    #pragma unroll
    for (int r = 0; r < 4; ++r) {
        float p = rp[r];
        #pragma unroll
        for (int m = 1; m <= 8; m <<= 1) p += __shfl_xor(p, m);
        if (c15 == 0) {
            int orow = blockIdx.x * 64 + w * 16 + g * 4 + r;
            out[N + orow] = 1.f / (1.f + expf(-(p + rb2[0])));
        }
    }

    // z1 -> Zh (bf16, A-frag order)
    {
        unsigned short* zp = (unsigned short*)Zh;
        #pragma unroll
        for (int nt = 0; nt < 8; ++nt) {
            int c = nt * 16 + c15;
            float bb = mb1[c];
            #pragma unroll
            for (int r = 0; r < 4; ++r) {
                float v = fmaxf(z1[nt][r] + bb, 0.f);
                int lanep = ((nt * 2 + (c15 >> 3)) & 3) * 16 + g * 4 + r;
                zp[((w * 4 + (nt >> 1)) * 64 + lanep) * 8 + (c15 & 7)] = (unsigned short)bfr(v);
            }
        }
    }
    __syncthreads();

    f32x4 z2a[4];
    #pragma unroll
    for (int i = 0; i < 4; ++i) z2a[i] = (f32x4){0.f, 0.f, 0.f, 0.f};
    #pragma unroll
    for (int ks2 = 0; ks2 < 4; ++ks2) {
        u32x4 za = Zh[(w * 4 + ks2) * 64 + l];
        #pragma unroll
        for (int nt2 = 0; nt2 < 4; ++nt2)
            z2a[nt2] = MFMA(za, W2h4[(ks2 * 4 + nt2) * 64 + l], z2a[nt2]);
    }
    float wp[4] = {0.f, 0.f, 0.f, 0.f};
    #pragma unroll
    for (int nt2 = 0; nt2 < 4; ++nt2) {
        int c = nt2 * 16 + c15;
        float bb = mb2[c], w3 = mW3[c];
        #pragma unroll
        for (int r = 0; r < 4; ++r) wp[r] += fmaxf(z2a[nt2][r] + bb, 0.f) * w3;
    }
    #pragma unroll
    for (int r = 0; r < 4; ++r) {
        float p = wp[r];
        #pragma unroll
        for (int m = 1; m <= 8; m <<= 1) p += __shfl_xor(p, m);
        if (c15 == 0) {
            int orow = blockIdx.x * 64 + w * 16 + g * 4 + r;
            out[orow] = p + mb3[0];
        }
    }
}

extern "C" void kernel_launch(void* const* d_in, const int* in_sizes, int n_in,
                              void* d_out, int out_size, void* d_ws, size_t ws_size,
                              hipStream_t stream) {
    const float* X        = (const float*)d_in[0];
    const float* A        = (const float*)d_in[1];
    const int*   v1_idx   = (const int*)d_in[2];
    const int*   v2_idx   = (const int*)d_in[3];
    const int*   seat     = (const int*)d_in[4];
    const float* W0       = (const float*)d_in[5];
    const float* b0       = (const float*)d_in[6];
    const float* g0       = (const float*)d_in[7];
    const float* be0      = (const float*)d_in[8];
    const float* W1       = (const float*)d_in[9];
    const float* b1       = (const float*)d_in[10];
    const float* g1       = (const float*)d_in[11];
    const float* be1      = (const float*)d_in[12];
    const float* W2       = (const float*)d_in[13];
    const float* b2       = (const float*)d_in[14];
    const float* g2       = (const float*)d_in[15];
    const float* be2      = (const float*)d_in[16];
    const float* seat_emb = (const float*)d_in[17];
    const float* mW1      = (const float*)d_in[18];
    const float* mb1      = (const float*)d_in[19];
    const float* mW2      = (const float*)d_in[20];
    const float* mb2      = (const float*)d_in[21];
    const float* mW3      = (const float*)d_in[22];
    const float* mb3      = (const float*)d_in[23];
    const float* rW1      = (const float*)d_in[24];
    const float* rb1      = (const float*)d_in[25];
    const float* rW2      = (const float*)d_in[26];
    const float* rb2      = (const float*)d_in[27];

    const int N = in_sizes[2];           // 16384
    float* out = (float*)d_out;

    // ws layout: hws [N][400] fp32 (26,214,400 B) | W1h | W1l | R1h | W2h
    float*    hws = (float*)d_ws;
    unsigned* W1h = (unsigned*)((char*)d_ws + (size_t)N * HROW * 4);
    unsigned* W1l = W1h + 26624;
    unsigned* R1h = W1l + 26624;
    unsigned* W2h = R1h + 13312;         // total 26,497,024 B (< proven 27.3MB)

    head_frag_init<<<104, 256, 0, stream>>>(mW1, rW1, mW2, W1h, W1l, R1h, W2h);

    const int spb = 8;
    const int gridA = N / spb;           // 2048
    gcn_mfma<<<gridA, 256, 0, stream>>>(
        X, A, v1_idx, v2_idx, seat,
        W0, b0, g0, be0, W1, b1, g1, be1, W2, b2, g2, be2,
        seat_emb, hws, spb);

    const int gridB = N / 64;            // 256
    head_mfma<<<gridB, 256, 0, stream>>>(
        hws, W1h, W1l, R1h, W2h,
        mb1, mb2, mW3, mb3, rb1, rW2, rb2, out, N);
}